// Round 1
// 1610.513 us; speedup vs baseline: 1.1715x; 1.1715x over previous
//
#include <hip/hip_runtime.h>
#include <math.h>

// Problem constants (fixed by the reference)
#define NP    100000      // primal nodes
#define EP    1600000     // primal edges
#define NDU   1600000     // dual nodes
#define EDU   3200000     // dual edges
#define FIN   512
#define NHEAD 8
#define HIDC  8
#define NCLS  16
#define NEGS  0.2f
#define TPB   256

static __device__ __forceinline__ float lrelu(float x){ return x > 0.f ? x : NEGS*x; }

// ===================== CSR build (per-dst) =====================
// hist -> 3-kernel exclusive scan -> fill (mutates offs so offs[d] ends at
// segment end; gather uses beg = d? offs[d-1]:0, end = offs[d]).

__global__ void k_hist(const int* __restrict__ dst, int* __restrict__ deg, int n){
  int e = blockIdx.x*TPB + threadIdx.x;
  if(e < n) atomicAdd(deg + dst[e], 1);
}

// block = 256 threads x 8 elems = 2048
__global__ void k_scan1(const int* __restrict__ deg, int* __restrict__ offs,
                        int* __restrict__ bsum, int n){
  __shared__ int lds[TPB];
  const int tid = threadIdx.x;
  const int base = blockIdx.x*2048 + tid*8;
  int ex[8]; int s = 0;
  #pragma unroll
  for(int i=0;i<8;i++){ int idx=base+i; int x = (idx<n)? deg[idx] : 0; ex[i]=s; s+=x; }
  lds[tid] = s; __syncthreads();
  for(int off=1; off<TPB; off<<=1){
    int t = (tid>=off)? lds[tid-off] : 0;
    __syncthreads(); lds[tid] += t; __syncthreads();
  }
  int thrExcl = lds[tid] - s;
  if(tid == TPB-1) bsum[blockIdx.x] = lds[TPB-1];
  #pragma unroll
  for(int i=0;i<8;i++){ int idx=base+i; if(idx<n) offs[idx] = thrExcl + ex[i]; }
}

// single block, up to 1024 block sums, exclusive in place
__global__ void k_scan2(int* __restrict__ bs, int nb){
  __shared__ int lds[TPB];
  const int tid = threadIdx.x;
  int v[4]; int s = 0;
  #pragma unroll
  for(int i=0;i<4;i++){ int idx=tid*4+i; int x = (idx<nb)? bs[idx] : 0; v[i]=s; s+=x; }
  lds[tid] = s; __syncthreads();
  for(int off=1; off<TPB; off<<=1){
    int t = (tid>=off)? lds[tid-off] : 0;
    __syncthreads(); lds[tid] += t; __syncthreads();
  }
  int thrExcl = lds[tid] - s;
  #pragma unroll
  for(int i=0;i<4;i++){ int idx=tid*4+i; if(idx<nb) bs[idx] = thrExcl + v[i]; }
}

__global__ void k_scan3(int* __restrict__ offs, const int* __restrict__ bs, int n){
  int i = blockIdx.x*TPB + threadIdx.x;
  if(i < n) offs[i] += bs[i>>11];
}

__global__ void k_fill(const int* __restrict__ src, const int* __restrict__ dst,
                       int* __restrict__ offs, int* __restrict__ col, int n){
  int e = blockIdx.x*TPB + threadIdx.x;
  if(e >= n) return;
  int pos = atomicAdd(offs + dst[e], 1);
  col[pos] = src[e];
}

// dinv[i] = rsqrt(deg+1), written in place over the int deg array
__global__ void k_dinv(int* __restrict__ degio, int n){
  int i = blockIdx.x*TPB + threadIdx.x;
  if(i >= n) return;
  int d = degio[i];
  ((float*)degio)[i] = rsqrtf((float)d + 1.0f);
}

// ===================== dual (line-graph) GCN branch =====================
// Layer 1 fused gather: Q1[d][c] = relu(dinv[d]*( sum_{s in N(d)} g(s,c) + g(d,c) ) + bg1[c])
// with g(n,c) = dinv[n] * sum_k dx[n][k]*Wg1[k][c]   (h1 never materialized)
__global__ void k_dgath1(const float* __restrict__ dx, const float* __restrict__ Wg1,
                         const float* __restrict__ bg1, const float* __restrict__ dinv,
                         const int* __restrict__ offs, const int* __restrict__ col,
                         float* __restrict__ Q1){
  int t = blockIdx.x*TPB + threadIdx.x;   // over NDU*8
  if(t >= NDU*8) return;
  int d = t >> 3, c = t & 7;
  const float w0 = Wg1[c], w1 = Wg1[8+c], w2 = Wg1[16+c], w3 = Wg1[24+c];
  int beg = d ? offs[d-1] : 0;
  int end = offs[d];
  const float4 xd = *(const float4*)(dx + d*4);
  float acc = dinv[d]*(xd.x*w0 + xd.y*w1 + xd.z*w2 + xd.w*w3);  // self loop
  for(int j=beg; j<end; j++){
    int s = col[j];
    const float4 xs = *(const float4*)(dx + s*4);
    acc += dinv[s]*(xs.x*w0 + xs.y*w1 + xs.z*w2 + xs.w*w3);
  }
  float v = dinv[d]*acc + bg1[c];
  Q1[t] = v > 0.f ? v : 0.f;
}

// Layer 2 fused gather: Qo[d][c] = dinv[d]*( sum g2(s,c) + g2(d,c) ) + bg2[c]
// with g2(n,c) = dinv[n]*sum_k Q1[n][k]*Wg2[k][c]
__global__ void k_dgath2(const float* __restrict__ Q1, const float* __restrict__ Wg2,
                         const float* __restrict__ bg2, const float* __restrict__ dinv,
                         const int* __restrict__ offs, const int* __restrict__ col,
                         float* __restrict__ Qo){
  int t = blockIdx.x*TPB + threadIdx.x;   // over NDU*16
  if(t >= NDU*16) return;
  int d = t >> 4, c = t & 15;
  float w[8];
  #pragma unroll
  for(int k=0;k<8;k++) w[k] = Wg2[k*16+c];
  int beg = d ? offs[d-1] : 0;
  int end = offs[d];
  float acc;
  {
    float g = 0.f;
    #pragma unroll
    for(int k=0;k<8;k++) g += Q1[d*8+k]*w[k];
    acc = dinv[d]*g;                      // self loop
  }
  for(int j=beg; j<end; j++){
    int s = col[j];
    float g = 0.f;
    #pragma unroll
    for(int k=0;k<8;k++) g += Q1[s*8+k]*w[k];
    acc += dinv[s]*g;
  }
  Qo[t] = dinv[d]*acc + bg2[c];
}

// ===================== primal GAT branch =====================

// H = x @ W1 : [100000,512]x[512,64], fp32 (no fp32 MFMA on CDNA4 -> vector GEMM).
// Register-tiled: BM=128 rows x 64 cols per block, BK=32.
// 256 threads, each computes an 8x4 register tile (32 acc).
// x staged TRANSPOSED in LDS ([BK][BM+4] pad -> 16B-aligned ds_read_b128,
// conflict-free broadcast reads); W staged [BK][64].
// Per kk: 3x ds_read_b128 + 32 FMA -> FMA-dominated (old version: 4 FMA per
// L2-latency W load -> 14% VALUBusy, 415 us).
#define GBM 128
#define GBK 32
__global__ __launch_bounds__(TPB) void k_gemm1(const float* __restrict__ x,
                                               const float* __restrict__ W,
                                               float* __restrict__ H){
  __shared__ float xs[GBK][GBM+4];   // 32x132 floats = 16.5 KB, transposed
  __shared__ float ws[GBK][64];      // 8 KB
  const int tx = threadIdx.x;
  const int r0 = blockIdx.x*GBM;
  const int cg = tx & 15;            // col group: cols cg*4..cg*4+3
  const int rg = tx >> 4;            // row group 0..15: rows rg*8..rg*8+7

  float acc[8][4];
  #pragma unroll
  for(int i=0;i<8;i++)
    #pragma unroll
    for(int j=0;j<4;j++) acc[i][j] = 0.f;

  // x staging: tile = 128 rows x 32 k = 1024 float4 chunks, 4 per thread.
  // chunk c (=q*256+tx): row = c>>3, kc = (c&7)*4
  const int xrow = tx >> 3;          // 0..31 (+32*q)
  const int xkc  = (tx & 7) * 4;     // 0,4,...,28
  // W staging: 32x64 = 512 float4 chunks, 2 per thread.
  const int wk = tx >> 4;            // 0..15 (+16)
  const int wc = (tx & 15) * 4;

  for(int k0=0; k0<FIN; k0+=GBK){
    // stage x (transposed into LDS)
    #pragma unroll
    for(int q=0;q<4;q++){
      int r  = xrow + q*32;
      int gr = r0 + r;
      float4 v = (gr < NP) ? *(const float4*)(x + (size_t)gr*FIN + k0 + xkc)
                           : make_float4(0.f,0.f,0.f,0.f);
      xs[xkc+0][r] = v.x; xs[xkc+1][r] = v.y;
      xs[xkc+2][r] = v.z; xs[xkc+3][r] = v.w;
    }
    // stage W
    #pragma unroll
    for(int q=0;q<2;q++){
      int k = wk + q*16;
      *(float4*)(&ws[k][wc]) = *(const float4*)(W + (size_t)(k0+k)*64 + wc);
    }
    __syncthreads();
    #pragma unroll 8
    for(int kk=0;kk<GBK;kk++){
      const float4 a0 = *(const float4*)(&xs[kk][rg*8]);
      const float4 a1 = *(const float4*)(&xs[kk][rg*8+4]);
      const float4 b  = *(const float4*)(&ws[kk][cg*4]);
      const float av[8] = {a0.x,a0.y,a0.z,a0.w,a1.x,a1.y,a1.z,a1.w};
      const float bv[4] = {b.x,b.y,b.z,b.w};
      #pragma unroll
      for(int i=0;i<8;i++)
        #pragma unroll
        for(int j=0;j<4;j++)
          acc[i][j] += av[i]*bv[j];
    }
    __syncthreads();
  }
  #pragma unroll
  for(int i=0;i<8;i++){
    int gr = r0 + rg*8 + i;
    if(gr < NP)
      *(float4*)(H + (size_t)gr*64 + cg*4) =
          make_float4(acc[i][0],acc[i][1],acc[i][2],acc[i][3]);
  }
}

__global__ void k_alpha(const float* __restrict__ H, const float* __restrict__ aw_s,
                        const float* __restrict__ aw_d,
                        float* __restrict__ als, float* __restrict__ ald){
  int i = blockIdx.x*TPB + threadIdx.x;     // over NP*8
  if(i >= NP*NHEAD) return;
  int n = i >> 3, h = i & 7;
  const float* hp = H + n*64 + h*8;
  float s = 0.f, d = 0.f;
  #pragma unroll
  for(int c=0;c<8;c++){ float v = hp[c]; s += v*aw_s[h*8+c]; d += v*aw_d[h*8+c]; }
  als[i] = s; ald[i] = d;
}

// GAT layer-1 gather: one wave per dst node; in-wave softmax (no segment_max:
// |logit| <~ 6 so exp() is fp32-safe and softmax is shift-invariant).
// Phase 1: 8 edges x 8 heads per iter -> den[h]. Phase 2: 64 lanes = channels.
// Fused: + b1, ELU.
__global__ __launch_bounds__(TPB) void k_agg1(const int* __restrict__ offs,
                                              const int* __restrict__ col,
                                              const float* __restrict__ als,
                                              const float* __restrict__ ald,
                                              const float* __restrict__ H,
                                              const float* __restrict__ b1,
                                              float* __restrict__ O){
  int d = (blockIdx.x*TPB + threadIdx.x) >> 6;   // wave per dst; grid covers NP exactly
  int lane = threadIdx.x & 63;
  int beg = d ? offs[d-1] : 0;
  int end = offs[d];
  // phase 1: denominator per head
  int h1 = lane & 7;
  float aldv = ald[d*8 + h1];
  float den = 0.f;
  for(int j0=beg; j0<end; j0+=8){
    int j = j0 + (lane>>3);
    if(j < end){
      int s = col[j];
      den += __expf(lrelu(als[s*8 + h1] + aldv));
    }
  }
  den += __shfl_xor(den, 8);
  den += __shfl_xor(den, 16);
  den += __shfl_xor(den, 32);
  den += __expf(lrelu(als[d*8 + h1] + aldv));      // self loop
  // phase 2: lane = output channel, head = lane>>3
  int hc = lane >> 3;
  float denc = __shfl(den, hc);     // lane hc holds den for head hc
  float aldc = __shfl(aldv, hc);
  float inv = 1.f / (denc + 1e-16f);
  float acc = 0.f;
  for(int j=beg; j<end; j++){
    int s = col[j];
    float w = __expf(lrelu(als[s*8 + hc] + aldc)) * inv;
    acc += w * H[s*64 + lane];
  }
  float ws = __expf(lrelu(als[d*8 + hc] + aldc)) * inv;
  acc += ws * H[d*64 + lane];
  float v = acc + b1[lane];
  O[d*64 + lane] = v > 0.f ? v : expm1f(v);        // ELU fused
}

// G = O @ W2 ([64][16]) + layer-2 attention logits (heads=1)
__global__ void k_g(const float* __restrict__ O, const float* __restrict__ W2,
                    const float* __restrict__ asw, const float* __restrict__ adw,
                    float* __restrict__ G, float* __restrict__ as2, float* __restrict__ ad2){
  __shared__ float w2s[64*NCLS];
  for(int i=threadIdx.x; i<64*NCLS; i+=TPB) w2s[i] = W2[i];
  __syncthreads();
  int n = blockIdx.x*TPB + threadIdx.x;
  if(n >= NP) return;
  float g[16];
  #pragma unroll
  for(int c=0;c<16;c++) g[c] = 0.f;
  const float* op = O + n*64;
  #pragma unroll
  for(int k4=0;k4<64;k4+=4){
    float4 v = *(const float4*)(op + k4);
    #pragma unroll
    for(int c=0;c<16;c++){
      g[c] += v.x*w2s[(k4+0)*16+c] + v.y*w2s[(k4+1)*16+c]
            + v.z*w2s[(k4+2)*16+c] + v.w*w2s[(k4+3)*16+c];
    }
  }
  float s=0.f, t=0.f;
  #pragma unroll
  for(int c=0;c<16;c++){ s += g[c]*asw[c]; t += g[c]*adw[c]; }
  #pragma unroll
  for(int c4=0;c4<16;c4+=4)
    *(float4*)(G + n*16 + c4) = make_float4(g[c4],g[c4+1],g[c4+2],g[c4+3]);
  as2[n] = s; ad2[n] = t;
}

// GAT layer-2 gather: one wave per dst. Phase 1: 64 edges/iter -> den.
// Phase 2: 4 edges x 16 channels. Fused + b2 -> final output.
__global__ __launch_bounds__(TPB) void k_agg2(const int* __restrict__ offs,
                                              const int* __restrict__ col,
                                              const float* __restrict__ as2,
                                              const float* __restrict__ ad2,
                                              const float* __restrict__ G,
                                              const float* __restrict__ b2,
                                              float* __restrict__ out){
  int d = (blockIdx.x*TPB + threadIdx.x) >> 6;
  int lane = threadIdx.x & 63;
  int beg = d ? offs[d-1] : 0;
  int end = offs[d];
  float ad2d = ad2[d];
  float den = 0.f;
  for(int j0=beg; j0<end; j0+=64){
    int j = j0 + lane;
    if(j < end) den += __expf(lrelu(as2[col[j]] + ad2d));
  }
  #pragma unroll
  for(int off=32; off; off>>=1) den += __shfl_xor(den, off);
  den += __expf(lrelu(as2[d] + ad2d));             // self loop
  float inv = 1.f / (den + 1e-16f);
  int c = lane & 15, slot = lane >> 4;
  float acc = 0.f;
  for(int j0=beg; j0<end; j0+=4){
    int j = j0 + slot;
    if(j < end){
      int s = col[j];
      acc += __expf(lrelu(as2[s] + ad2d)) * inv * G[s*16 + c];
    }
  }
  acc += __shfl_xor(acc, 16);
  acc += __shfl_xor(acc, 32);
  acc += __expf(lrelu(as2[d] + ad2d)) * inv * G[d*16 + c];   // self loop
  if(lane < 16) out[d*16 + c] = acc + b2[c];
}

// ===================== launch =====================

extern "C" void kernel_launch(void* const* d_in, const int* in_sizes, int n_in,
                              void* d_out, int out_size, void* d_ws, size_t ws_size,
                              hipStream_t stream){
  const float* x    = (const float*)d_in[0];
  const int*   ei   = (const int*)  d_in[1];
  const float* dx   = (const float*)d_in[2];
  const int*   dei  = (const int*)  d_in[3];
  const float* W1   = (const float*)d_in[4];
  const float* aw1s = (const float*)d_in[5];
  const float* aw1d = (const float*)d_in[6];
  const float* b1   = (const float*)d_in[7];
  const float* W2   = (const float*)d_in[8];
  const float* aw2s = (const float*)d_in[9];
  const float* aw2d = (const float*)d_in[10];
  const float* b2   = (const float*)d_in[11];
  const float* Wg1  = (const float*)d_in[12];
  const float* bg1  = (const float*)d_in[13];
  const float* Wg2  = (const float*)d_in[14];
  const float* bg2  = (const float*)d_in[15];

  float* out = (float*)d_out;          // [NP,16]
  float* Qo  = out + NP*NCLS;          // [NDU,16]

  // workspace layout (4B words), total ~32M words = 128 MB:
  //   R[25.6M]  -- dual: Q1 (12.8M); primal: H1|O1|G|als|ald|as2|ad2|offsP|colP
  //   dinv/degD[1.6M] | offsD[1.6M] | colD[3.2M] | bsum[1024]
  float* R     = (float*)d_ws;
  int*   degD  = (int*)(R + 25600000);      // becomes float dinv in place
  int*   offsD = degD + 1600000;
  int*   colD  = offsD + 1600000;
  int*   bsum  = colD + 3200000;            // 1024
  float* dinvF = (float*)degD;

  // dual-phase overlay
  float* Q1   = R;                    // 12.8M
  // primal-phase overlay (dual branch fully finished before primal gathers)
  float* H1   = R;                    // 6.4M
  float* O1   = R + 6400000;          // 6.4M
  float* G    = R + 12800000;         // 1.6M
  float* als  = R + 14400000;         // 0.8M
  float* ald  = R + 15200000;         // 0.8M
  float* as2  = R + 16000000;         // 0.1M
  float* ad2  = R + 16100000;         // 0.1M
  int*   degP = (int*)(R + 16200000); // 0.1M
  int*   offsP= degP + 100000;        // 0.1M
  int*   colP = offsP + 100000;       // 1.6M

  const int* dsrc = dei;
  const int* ddst = dei + EDU;
  const int* esrc = ei;
  const int* edst = ei + EP;

  // ---- dual CSR build ----
  hipMemsetAsync(degD, 0, (size_t)NDU*sizeof(int), stream);
  k_hist <<<EDU/TPB, TPB, 0, stream>>>(ddst, degD, EDU);
  k_scan1<<<(NDU+2047)/2048, TPB, 0, stream>>>(degD, offsD, bsum, NDU);
  k_scan2<<<1, TPB, 0, stream>>>(bsum, (NDU+2047)/2048);
  k_scan3<<<NDU/TPB, TPB, 0, stream>>>(offsD, bsum, NDU);
  k_dinv <<<NDU/TPB, TPB, 0, stream>>>(degD, NDU);            // degD -> dinv (float, in place)
  k_fill <<<EDU/TPB, TPB, 0, stream>>>(dsrc, ddst, offsD, colD, EDU);

  // ---- dual GCN (fused gathers, weights applied on the fly) ----
  k_dgath1<<<NDU*8/TPB,  TPB, 0, stream>>>(dx, Wg1, bg1, dinvF, offsD, colD, Q1);
  k_dgath2<<<NDU*16/TPB, TPB, 0, stream>>>(Q1, Wg2, bg2, dinvF, offsD, colD, Qo);

  // ---- primal CSR build ----
  hipMemsetAsync(degP, 0, (size_t)NP*sizeof(int), stream);
  k_hist <<<EP/TPB, TPB, 0, stream>>>(edst, degP, EP);
  k_scan1<<<(NP+2047)/2048, TPB, 0, stream>>>(degP, offsP, bsum, NP);
  k_scan2<<<1, TPB, 0, stream>>>(bsum, (NP+2047)/2048);
  k_scan3<<<(NP+TPB-1)/TPB, TPB, 0, stream>>>(offsP, bsum, NP);
  k_fill <<<EP/TPB, TPB, 0, stream>>>(esrc, edst, offsP, colP, EP);

  // ---- primal GAT ----
  k_gemm1<<<(NP+GBM-1)/GBM, TPB, 0, stream>>>(x, W1, H1);
  k_alpha<<<NP*NHEAD/TPB, TPB, 0, stream>>>(H1, aw1s, aw1d, als, ald);
  k_agg1 <<<NP/4, TPB, 0, stream>>>(offsP, colP, als, ald, H1, b1, O1);
  k_g    <<<(NP+TPB-1)/TPB, TPB, 0, stream>>>(O1, W2, aw2s, aw2d, G, as2, ad2);
  k_agg2 <<<NP/4, TPB, 0, stream>>>(offsP, colP, as2, ad2, G, b2, out);
}

// Round 2
// 1590.180 us; speedup vs baseline: 1.1865x; 1.0128x over previous
//
#include <hip/hip_runtime.h>
#include <math.h>

// Problem constants (fixed by the reference)
#define NP    100000      // primal nodes
#define EP    1600000     // primal edges
#define NDU   1600000     // dual nodes
#define EDU   3200000     // dual edges
#define FIN   512
#define NHEAD 8
#define HIDC  8
#define NCLS  16
#define NEGS  0.2f
#define TPB   256

static __device__ __forceinline__ float lrelu(float x){ return x > 0.f ? x : NEGS*x; }

// ===================== CSR build (per-dst), bucketed =====================
// R1 finding: flat k_fill was random-line transaction bound (WRITE_SIZE 208MB
// = 3.2M x 64B lines for 12.8MB of payload; VALUBusy 0.3%, hbm 10%).
// Fix: MSD-radix bucket by dst>>shift (98 buckets) -> bucketed (src,dst)
// pairs, then hist/fill over bucketed pairs so atomics+writes hit a 64-128KB
// L2-resident window per bucket. Segment order stays arbitrary (atomicAdd),
// same as before -- gather sums are order-agnostic.

#define BKT_MAX 128   // >= actual bucket count (98)
#define BCHUNK  2048  // edges per block in bucket kernels (8/thread)

// per-block LDS histogram of dst>>shift -> global bucket counts
__global__ void k_bhist(const int* __restrict__ dst, int* __restrict__ bcnt,
                        int n, int shift){
  __shared__ int cnt[BKT_MAX];
  for(int i=threadIdx.x;i<BKT_MAX;i+=TPB) cnt[i]=0;
  __syncthreads();
  int base = blockIdx.x*BCHUNK;
  #pragma unroll
  for(int i=0;i<8;i++){
    int e = base + i*TPB + threadIdx.x;
    if(e<n) atomicAdd(&cnt[dst[e]>>shift],1);
  }
  __syncthreads();
  for(int i=threadIdx.x;i<BKT_MAX;i+=TPB) if(cnt[i]) atomicAdd(bcnt+i, cnt[i]);
}

// exclusive scan of <=BKT_MAX bucket counts, in place (tiny; serial in LDS)
__global__ void k_bscan(int* __restrict__ bcnt, int nb){
  __shared__ int lds[BKT_MAX];
  for(int i=threadIdx.x;i<nb;i+=TPB) lds[i]=bcnt[i];
  __syncthreads();
  if(threadIdx.x==0){ int s=0; for(int i=0;i<nb;i++){ int v=lds[i]; lds[i]=s; s+=v; } }
  __syncthreads();
  for(int i=threadIdx.x;i<nb;i+=TPB) bcnt[i]=lds[i];
}

// block-local counting scatter: edges -> bucketed (src,dst) pairs.
// Per block: LDS rank within (block,bucket), ONE global atomicAdd per bucket,
// then writes land in ~21-pair (168B) contiguous runs per bucket.
__global__ __launch_bounds__(TPB) void k_bscat(const int* __restrict__ src,
                                               const int* __restrict__ dst,
                                               int* __restrict__ btail,
                                               int2* __restrict__ pairs,
                                               int n, int shift){
  __shared__ int cnt[BKT_MAX];
  __shared__ int bbase[BKT_MAX];
  for(int i=threadIdx.x;i<BKT_MAX;i+=TPB) cnt[i]=0;
  __syncthreads();
  int base = blockIdx.x*BCHUNK;
  int sv[8], dv[8], rv[8];
  #pragma unroll
  for(int i=0;i<8;i++){
    int e = base + i*TPB + threadIdx.x;
    if(e<n){ sv[i]=src[e]; dv[i]=dst[e]; rv[i]=atomicAdd(&cnt[dv[i]>>shift],1); }
    else rv[i]=-1;
  }
  __syncthreads();
  for(int i=threadIdx.x;i<BKT_MAX;i+=TPB){
    int c = cnt[i];
    bbase[i] = c ? atomicAdd(btail+i, c) : 0;
  }
  __syncthreads();
  #pragma unroll
  for(int i=0;i<8;i++){
    if(rv[i]>=0){
      int b = dv[i]>>shift;
      pairs[bbase[b]+rv[i]] = make_int2(sv[i], dv[i]);
    }
  }
}

// hist over bucketed pairs: block's 256 edges share one bucket's node window
__global__ void k_hist2(const int2* __restrict__ pairs, int* __restrict__ deg, int n){
  int e = blockIdx.x*TPB + threadIdx.x;
  if(e<n) atomicAdd(deg + pairs[e].y, 1);
}

// fill over bucketed pairs: atomics + col writes confined to bucket window
__global__ void k_fill2(const int2* __restrict__ pairs, int* __restrict__ offs,
                        int* __restrict__ col, int n){
  int e = blockIdx.x*TPB + threadIdx.x;
  if(e>=n) return;
  int2 p = pairs[e];
  int pos = atomicAdd(offs + p.y, 1);
  col[pos] = p.x;
}

// block = 256 threads x 8 elems = 2048
__global__ void k_scan1(const int* __restrict__ deg, int* __restrict__ offs,
                        int* __restrict__ bsum, int n){
  __shared__ int lds[TPB];
  const int tid = threadIdx.x;
  const int base = blockIdx.x*2048 + tid*8;
  int ex[8]; int s = 0;
  #pragma unroll
  for(int i=0;i<8;i++){ int idx=base+i; int x = (idx<n)? deg[idx] : 0; ex[i]=s; s+=x; }
  lds[tid] = s; __syncthreads();
  for(int off=1; off<TPB; off<<=1){
    int t = (tid>=off)? lds[tid-off] : 0;
    __syncthreads(); lds[tid] += t; __syncthreads();
  }
  int thrExcl = lds[tid] - s;
  if(tid == TPB-1) bsum[blockIdx.x] = lds[TPB-1];
  #pragma unroll
  for(int i=0;i<8;i++){ int idx=base+i; if(idx<n) offs[idx] = thrExcl + ex[i]; }
}

// single block, up to 1024 block sums, exclusive in place
__global__ void k_scan2(int* __restrict__ bs, int nb){
  __shared__ int lds[TPB];
  const int tid = threadIdx.x;
  int v[4]; int s = 0;
  #pragma unroll
  for(int i=0;i<4;i++){ int idx=tid*4+i; int x = (idx<nb)? bs[idx] : 0; v[i]=s; s+=x; }
  lds[tid] = s; __syncthreads();
  for(int off=1; off<TPB; off<<=1){
    int t = (tid>=off)? lds[tid-off] : 0;
    __syncthreads(); lds[tid] += t; __syncthreads();
  }
  int thrExcl = lds[tid] - s;
  #pragma unroll
  for(int i=0;i<4;i++){ int idx=tid*4+i; if(idx<nb) bs[idx] = thrExcl + v[i]; }
}

__global__ void k_scan3(int* __restrict__ offs, const int* __restrict__ bs, int n){
  int i = blockIdx.x*TPB + threadIdx.x;
  if(i < n) offs[i] += bs[i>>11];
}

// dinv[i] = rsqrt(deg+1), written in place over the int deg array
__global__ void k_dinv(int* __restrict__ degio, int n){
  int i = blockIdx.x*TPB + threadIdx.x;
  if(i >= n) return;
  int d = degio[i];
  ((float*)degio)[i] = rsqrtf((float)d + 1.0f);
}

// ===================== dual (line-graph) GCN branch =====================
// Layer 1 fused gather: Q1[d][c] = relu(dinv[d]*( sum_{s in N(d)} g(s,c) + g(d,c) ) + bg1[c])
// with g(n,c) = dinv[n] * sum_k dx[n][k]*Wg1[k][c]   (h1 never materialized)
__global__ void k_dgath1(const float* __restrict__ dx, const float* __restrict__ Wg1,
                         const float* __restrict__ bg1, const float* __restrict__ dinv,
                         const int* __restrict__ offs, const int* __restrict__ col,
                         float* __restrict__ Q1){
  int t = blockIdx.x*TPB + threadIdx.x;   // over NDU*8
  if(t >= NDU*8) return;
  int d = t >> 3, c = t & 7;
  const float w0 = Wg1[c], w1 = Wg1[8+c], w2 = Wg1[16+c], w3 = Wg1[24+c];
  int beg = d ? offs[d-1] : 0;
  int end = offs[d];
  const float4 xd = *(const float4*)(dx + d*4);
  float acc = dinv[d]*(xd.x*w0 + xd.y*w1 + xd.z*w2 + xd.w*w3);  // self loop
  for(int j=beg; j<end; j++){
    int s = col[j];
    const float4 xs = *(const float4*)(dx + s*4);
    acc += dinv[s]*(xs.x*w0 + xs.y*w1 + xs.z*w2 + xs.w*w3);
  }
  float v = dinv[d]*acc + bg1[c];
  Q1[t] = v > 0.f ? v : 0.f;
}

// Layer 2 fused gather: Qo[d][c] = dinv[d]*( sum g2(s,c) + g2(d,c) ) + bg2[c]
// with g2(n,c) = dinv[n]*sum_k Q1[n][k]*Wg2[k][c]
__global__ void k_dgath2(const float* __restrict__ Q1, const float* __restrict__ Wg2,
                         const float* __restrict__ bg2, const float* __restrict__ dinv,
                         const int* __restrict__ offs, const int* __restrict__ col,
                         float* __restrict__ Qo){
  int t = blockIdx.x*TPB + threadIdx.x;   // over NDU*16
  if(t >= NDU*16) return;
  int d = t >> 4, c = t & 15;
  float w[8];
  #pragma unroll
  for(int k=0;k<8;k++) w[k] = Wg2[k*16+c];
  int beg = d ? offs[d-1] : 0;
  int end = offs[d];
  float acc;
  {
    float g = 0.f;
    #pragma unroll
    for(int k=0;k<8;k++) g += Q1[d*8+k]*w[k];
    acc = dinv[d]*g;                      // self loop
  }
  for(int j=beg; j<end; j++){
    int s = col[j];
    float g = 0.f;
    #pragma unroll
    for(int k=0;k<8;k++) g += Q1[s*8+k]*w[k];
    acc += dinv[s]*g;
  }
  Qo[t] = dinv[d]*acc + bg2[c];
}

// ===================== primal GAT branch =====================

// H = x @ W1 : [100000,512]x[512,64], fp32 (no fp32 MFMA on CDNA4 -> vector GEMM).
// Register-tiled: BM=128 rows x 64 cols per block, BK=32.
// 256 threads, each computes an 8x4 register tile (32 acc).
#define GBM 128
#define GBK 32
__global__ __launch_bounds__(TPB) void k_gemm1(const float* __restrict__ x,
                                               const float* __restrict__ W,
                                               float* __restrict__ H){
  __shared__ float xs[GBK][GBM+4];   // 32x132 floats = 16.5 KB, transposed
  __shared__ float ws[GBK][64];      // 8 KB
  const int tx = threadIdx.x;
  const int r0 = blockIdx.x*GBM;
  const int cg = tx & 15;            // col group: cols cg*4..cg*4+3
  const int rg = tx >> 4;            // row group 0..15: rows rg*8..rg*8+7

  float acc[8][4];
  #pragma unroll
  for(int i=0;i<8;i++)
    #pragma unroll
    for(int j=0;j<4;j++) acc[i][j] = 0.f;

  const int xrow = tx >> 3;          // 0..31 (+32*q)
  const int xkc  = (tx & 7) * 4;     // 0,4,...,28
  const int wk = tx >> 4;            // 0..15 (+16)
  const int wc = (tx & 15) * 4;

  for(int k0=0; k0<FIN; k0+=GBK){
    #pragma unroll
    for(int q=0;q<4;q++){
      int r  = xrow + q*32;
      int gr = r0 + r;
      float4 v = (gr < NP) ? *(const float4*)(x + (size_t)gr*FIN + k0 + xkc)
                           : make_float4(0.f,0.f,0.f,0.f);
      xs[xkc+0][r] = v.x; xs[xkc+1][r] = v.y;
      xs[xkc+2][r] = v.z; xs[xkc+3][r] = v.w;
    }
    #pragma unroll
    for(int q=0;q<2;q++){
      int k = wk + q*16;
      *(float4*)(&ws[k][wc]) = *(const float4*)(W + (size_t)(k0+k)*64 + wc);
    }
    __syncthreads();
    #pragma unroll 8
    for(int kk=0;kk<GBK;kk++){
      const float4 a0 = *(const float4*)(&xs[kk][rg*8]);
      const float4 a1 = *(const float4*)(&xs[kk][rg*8+4]);
      const float4 b  = *(const float4*)(&ws[kk][cg*4]);
      const float av[8] = {a0.x,a0.y,a0.z,a0.w,a1.x,a1.y,a1.z,a1.w};
      const float bv[4] = {b.x,b.y,b.z,b.w};
      #pragma unroll
      for(int i=0;i<8;i++)
        #pragma unroll
        for(int j=0;j<4;j++)
          acc[i][j] += av[i]*bv[j];
    }
    __syncthreads();
  }
  #pragma unroll
  for(int i=0;i<8;i++){
    int gr = r0 + rg*8 + i;
    if(gr < NP)
      *(float4*)(H + (size_t)gr*64 + cg*4) =
          make_float4(acc[i][0],acc[i][1],acc[i][2],acc[i][3]);
  }
}

__global__ void k_alpha(const float* __restrict__ H, const float* __restrict__ aw_s,
                        const float* __restrict__ aw_d,
                        float* __restrict__ als, float* __restrict__ ald){
  int i = blockIdx.x*TPB + threadIdx.x;     // over NP*8
  if(i >= NP*NHEAD) return;
  int n = i >> 3, h = i & 7;
  const float* hp = H + n*64 + h*8;
  float s = 0.f, d = 0.f;
  #pragma unroll
  for(int c=0;c<8;c++){ float v = hp[c]; s += v*aw_s[h*8+c]; d += v*aw_d[h*8+c]; }
  als[i] = s; ald[i] = d;
}

// GAT layer-1 gather: one wave per dst node; in-wave softmax (no segment_max:
// |logit| <~ 6 so exp() is fp32-safe and softmax is shift-invariant).
__global__ __launch_bounds__(TPB) void k_agg1(const int* __restrict__ offs,
                                              const int* __restrict__ col,
                                              const float* __restrict__ als,
                                              const float* __restrict__ ald,
                                              const float* __restrict__ H,
                                              const float* __restrict__ b1,
                                              float* __restrict__ O){
  int d = (blockIdx.x*TPB + threadIdx.x) >> 6;   // wave per dst; grid covers NP exactly
  int lane = threadIdx.x & 63;
  int beg = d ? offs[d-1] : 0;
  int end = offs[d];
  // phase 1: denominator per head
  int h1 = lane & 7;
  float aldv = ald[d*8 + h1];
  float den = 0.f;
  for(int j0=beg; j0<end; j0+=8){
    int j = j0 + (lane>>3);
    if(j < end){
      int s = col[j];
      den += __expf(lrelu(als[s*8 + h1] + aldv));
    }
  }
  den += __shfl_xor(den, 8);
  den += __shfl_xor(den, 16);
  den += __shfl_xor(den, 32);
  den += __expf(lrelu(als[d*8 + h1] + aldv));      // self loop
  // phase 2: lane = output channel, head = lane>>3
  int hc = lane >> 3;
  float denc = __shfl(den, hc);     // lane hc holds den for head hc
  float aldc = __shfl(aldv, hc);
  float inv = 1.f / (denc + 1e-16f);
  float acc = 0.f;
  for(int j=beg; j<end; j++){
    int s = col[j];
    float w = __expf(lrelu(als[s*8 + hc] + aldc)) * inv;
    acc += w * H[s*64 + lane];
  }
  float ws = __expf(lrelu(als[d*8 + hc] + aldc)) * inv;
  acc += ws * H[d*64 + lane];
  float v = acc + b1[lane];
  O[d*64 + lane] = v > 0.f ? v : expm1f(v);        // ELU fused
}

// G = O @ W2 ([64][16]) + layer-2 attention logits (heads=1)
__global__ void k_g(const float* __restrict__ O, const float* __restrict__ W2,
                    const float* __restrict__ asw, const float* __restrict__ adw,
                    float* __restrict__ G, float* __restrict__ as2, float* __restrict__ ad2){
  __shared__ float w2s[64*NCLS];
  for(int i=threadIdx.x; i<64*NCLS; i+=TPB) w2s[i] = W2[i];
  __syncthreads();
  int n = blockIdx.x*TPB + threadIdx.x;
  if(n >= NP) return;
  float g[16];
  #pragma unroll
  for(int c=0;c<16;c++) g[c] = 0.f;
  const float* op = O + n*64;
  #pragma unroll
  for(int k4=0;k4<64;k4+=4){
    float4 v = *(const float4*)(op + k4);
    #pragma unroll
    for(int c=0;c<16;c++){
      g[c] += v.x*w2s[(k4+0)*16+c] + v.y*w2s[(k4+1)*16+c]
            + v.z*w2s[(k4+2)*16+c] + v.w*w2s[(k4+3)*16+c];
    }
  }
  float s=0.f, t=0.f;
  #pragma unroll
  for(int c=0;c<16;c++){ s += g[c]*asw[c]; t += g[c]*adw[c]; }
  #pragma unroll
  for(int c4=0;c4<16;c4+=4)
    *(float4*)(G + n*16 + c4) = make_float4(g[c4],g[c4+1],g[c4+2],g[c4+3]);
  as2[n] = s; ad2[n] = t;
}

// GAT layer-2 gather: one wave per dst.
__global__ __launch_bounds__(TPB) void k_agg2(const int* __restrict__ offs,
                                              const int* __restrict__ col,
                                              const float* __restrict__ as2,
                                              const float* __restrict__ ad2,
                                              const float* __restrict__ G,
                                              const float* __restrict__ b2,
                                              float* __restrict__ out){
  int d = (blockIdx.x*TPB + threadIdx.x) >> 6;
  int lane = threadIdx.x & 63;
  int beg = d ? offs[d-1] : 0;
  int end = offs[d];
  float ad2d = ad2[d];
  float den = 0.f;
  for(int j0=beg; j0<end; j0+=64){
    int j = j0 + lane;
    if(j < end) den += __expf(lrelu(as2[col[j]] + ad2d));
  }
  #pragma unroll
  for(int off=32; off; off>>=1) den += __shfl_xor(den, off);
  den += __expf(lrelu(as2[d] + ad2d));             // self loop
  float inv = 1.f / (den + 1e-16f);
  int c = lane & 15, slot = lane >> 4;
  float acc = 0.f;
  for(int j0=beg; j0<end; j0+=4){
    int j = j0 + slot;
    if(j < end){
      int s = col[j];
      acc += __expf(lrelu(as2[s] + ad2d)) * inv * G[s*16 + c];
    }
  }
  acc += __shfl_xor(acc, 16);
  acc += __shfl_xor(acc, 32);
  acc += __expf(lrelu(as2[d] + ad2d)) * inv * G[d*16 + c];   // self loop
  if(lane < 16) out[d*16 + c] = acc + b2[c];
}

// ===================== launch =====================

extern "C" void kernel_launch(void* const* d_in, const int* in_sizes, int n_in,
                              void* d_out, int out_size, void* d_ws, size_t ws_size,
                              hipStream_t stream){
  const float* x    = (const float*)d_in[0];
  const int*   ei   = (const int*)  d_in[1];
  const float* dx   = (const float*)d_in[2];
  const int*   dei  = (const int*)  d_in[3];
  const float* W1   = (const float*)d_in[4];
  const float* aw1s = (const float*)d_in[5];
  const float* aw1d = (const float*)d_in[6];
  const float* b1   = (const float*)d_in[7];
  const float* W2   = (const float*)d_in[8];
  const float* aw2s = (const float*)d_in[9];
  const float* aw2d = (const float*)d_in[10];
  const float* b2   = (const float*)d_in[11];
  const float* Wg1  = (const float*)d_in[12];
  const float* bg1  = (const float*)d_in[13];
  const float* Wg2  = (const float*)d_in[14];
  const float* bg2  = (const float*)d_in[15];

  float* out = (float*)d_out;          // [NP,16]
  float* Qo  = out + NP*NCLS;          // [NDU,16]

  // workspace layout (4B words), total ~32M words = 128 MB:
  //   R[25.6M]  -- dual: pairsD (6.4M) then Q1 (12.8M);
  //                primal: H1|O1|G|als|ald|as2|ad2|degP|offsP|colP|pairsP
  //   dinv/degD[1.6M] | offsD[1.6M] | colD[3.2M] | bsum[1024] | bkt[128]
  float* R     = (float*)d_ws;
  int*   degD  = (int*)(R + 25600000);      // becomes float dinv in place
  int*   offsD = degD + 1600000;
  int*   colD  = offsD + 1600000;
  int*   bsum  = colD + 3200000;            // 1024
  int*   bkt   = bsum + 1024;               // 128 bucket counters
  float* dinvF = (float*)degD;

  // dual-phase overlay
  int2*  pairsD = (int2*)R;           // 3.2M int2 = 6.4M words (dead before Q1)
  float* Q1   = R;                    // 12.8M
  // primal-phase overlay (dual branch fully finished before primal gathers)
  float* H1   = R;                    // 6.4M
  float* O1   = R + 6400000;          // 6.4M
  float* G    = R + 12800000;         // 1.6M
  float* als  = R + 14400000;         // 0.8M
  float* ald  = R + 15200000;         // 0.8M
  float* as2  = R + 16000000;         // 0.1M
  float* ad2  = R + 16100000;         // 0.1M
  int*   degP = (int*)(R + 16200000); // 0.1M
  int*   offsP= degP + 100000;        // 0.1M
  int*   colP = offsP + 100000;       // 1.6M
  int2*  pairsP = (int2*)(R + 18000000); // 1.6M int2 = 3.2M words (dead before H1)

  const int* dsrc = dei;
  const int* ddst = dei + EDU;
  const int* esrc = ei;
  const int* edst = ei + EP;

  // bucket shifts: dual 1.6M nodes >>14 -> 98 buckets (16K-node / 64KB window);
  // primal 100K nodes >>10 -> 98 buckets (1K-node / 4KB window)
  const int SH_D = 14, NB_D = (NDU - 1 >> SH_D) + 1;   // 98
  const int SH_P = 10, NB_P = (NP  - 1 >> SH_P) + 1;   // 98

  // ---- dual CSR build (bucketed) ----
  hipMemsetAsync(degD, 0, (size_t)NDU*sizeof(int), stream);
  hipMemsetAsync(bkt,  0, BKT_MAX*sizeof(int), stream);
  k_bhist<<<(EDU+BCHUNK-1)/BCHUNK, TPB, 0, stream>>>(ddst, bkt, EDU, SH_D);
  k_bscan<<<1, TPB, 0, stream>>>(bkt, NB_D);
  k_bscat<<<(EDU+BCHUNK-1)/BCHUNK, TPB, 0, stream>>>(dsrc, ddst, bkt, pairsD, EDU, SH_D);
  k_hist2<<<EDU/TPB, TPB, 0, stream>>>(pairsD, degD, EDU);
  k_scan1<<<(NDU+2047)/2048, TPB, 0, stream>>>(degD, offsD, bsum, NDU);
  k_scan2<<<1, TPB, 0, stream>>>(bsum, (NDU+2047)/2048);
  k_scan3<<<NDU/TPB, TPB, 0, stream>>>(offsD, bsum, NDU);
  k_dinv <<<NDU/TPB, TPB, 0, stream>>>(degD, NDU);            // degD -> dinv (float, in place)
  k_fill2<<<EDU/TPB, TPB, 0, stream>>>(pairsD, offsD, colD, EDU);

  // ---- dual GCN (fused gathers, weights applied on the fly) ----
  k_dgath1<<<NDU*8/TPB,  TPB, 0, stream>>>(dx, Wg1, bg1, dinvF, offsD, colD, Q1);
  k_dgath2<<<NDU*16/TPB, TPB, 0, stream>>>(Q1, Wg2, bg2, dinvF, offsD, colD, Qo);

  // ---- primal CSR build (bucketed) ----
  hipMemsetAsync(degP, 0, (size_t)NP*sizeof(int), stream);
  hipMemsetAsync(bkt,  0, BKT_MAX*sizeof(int), stream);
  k_bhist<<<(EP+BCHUNK-1)/BCHUNK, TPB, 0, stream>>>(edst, bkt, EP, SH_P);
  k_bscan<<<1, TPB, 0, stream>>>(bkt, NB_P);
  k_bscat<<<(EP+BCHUNK-1)/BCHUNK, TPB, 0, stream>>>(esrc, edst, bkt, pairsP, EP, SH_P);
  k_hist2<<<EP/TPB, TPB, 0, stream>>>(pairsP, degP, EP);
  k_scan1<<<(NP+2047)/2048, TPB, 0, stream>>>(degP, offsP, bsum, NP);
  k_scan2<<<1, TPB, 0, stream>>>(bsum, (NP+2047)/2048);
  k_scan3<<<(NP+TPB-1)/TPB, TPB, 0, stream>>>(offsP, bsum, NP);
  k_fill2<<<EP/TPB, TPB, 0, stream>>>(pairsP, offsP, colP, EP);

  // ---- primal GAT ----
  k_gemm1<<<(NP+GBM-1)/GBM, TPB, 0, stream>>>(x, W1, H1);
  k_alpha<<<NP*NHEAD/TPB, TPB, 0, stream>>>(H1, aw1s, aw1d, als, ald);
  k_agg1 <<<NP/4, TPB, 0, stream>>>(offsP, colP, als, ald, H1, b1, O1);
  k_g    <<<(NP+TPB-1)/TPB, TPB, 0, stream>>>(O1, W2, aw2s, aw2d, G, as2, ad2);
  k_agg2 <<<NP/4, TPB, 0, stream>>>(offsP, colP, as2, ad2, G, b2, out);
}

// Round 3
// 1445.222 us; speedup vs baseline: 1.3055x; 1.1003x over previous
//
#include <hip/hip_runtime.h>
#include <math.h>

// Problem constants (fixed by the reference)
#define NP    100000      // primal nodes
#define EP    1600000     // primal edges
#define NDU   1600000     // dual nodes
#define EDU   3200000     // dual edges
#define FIN   512
#define NHEAD 8
#define HIDC  8
#define NCLS  16
#define NEGS  0.2f
#define TPB   256

static __device__ __forceinline__ float lrelu(float x){ return x > 0.f ? x : NEGS*x; }

// ===================== CSR build (per-dst), bucketed =====================
// R1 finding: flat k_fill was random-line transaction bound. Bucket by
// dst>>shift so hist/fill atomics + col writes hit an L2-resident window.

#define BKT_MAX 128   // >= actual bucket count (98)
#define BCHUNK  2048  // edges per block in bucket kernels (8/thread)

__global__ void k_bhist(const int* __restrict__ dst, int* __restrict__ bcnt,
                        int n, int shift){
  __shared__ int cnt[BKT_MAX];
  for(int i=threadIdx.x;i<BKT_MAX;i+=TPB) cnt[i]=0;
  __syncthreads();
  int base = blockIdx.x*BCHUNK;
  #pragma unroll
  for(int i=0;i<8;i++){
    int e = base + i*TPB + threadIdx.x;
    if(e<n) atomicAdd(&cnt[dst[e]>>shift],1);
  }
  __syncthreads();
  for(int i=threadIdx.x;i<BKT_MAX;i+=TPB) if(cnt[i]) atomicAdd(bcnt+i, cnt[i]);
}

__global__ void k_bscan(int* __restrict__ bcnt, int nb){
  __shared__ int lds[BKT_MAX];
  for(int i=threadIdx.x;i<nb;i+=TPB) lds[i]=bcnt[i];
  __syncthreads();
  if(threadIdx.x==0){ int s=0; for(int i=0;i<nb;i++){ int v=lds[i]; lds[i]=s; s+=v; } }
  __syncthreads();
  for(int i=threadIdx.x;i<nb;i+=TPB) bcnt[i]=lds[i];
}

__global__ __launch_bounds__(TPB) void k_bscat(const int* __restrict__ src,
                                               const int* __restrict__ dst,
                                               int* __restrict__ btail,
                                               int2* __restrict__ pairs,
                                               int n, int shift){
  __shared__ int cnt[BKT_MAX];
  __shared__ int bbase[BKT_MAX];
  for(int i=threadIdx.x;i<BKT_MAX;i+=TPB) cnt[i]=0;
  __syncthreads();
  int base = blockIdx.x*BCHUNK;
  int sv[8], dv[8], rv[8];
  #pragma unroll
  for(int i=0;i<8;i++){
    int e = base + i*TPB + threadIdx.x;
    if(e<n){ sv[i]=src[e]; dv[i]=dst[e]; rv[i]=atomicAdd(&cnt[dv[i]>>shift],1); }
    else rv[i]=-1;
  }
  __syncthreads();
  for(int i=threadIdx.x;i<BKT_MAX;i+=TPB){
    int c = cnt[i];
    bbase[i] = c ? atomicAdd(btail+i, c) : 0;
  }
  __syncthreads();
  #pragma unroll
  for(int i=0;i<8;i++){
    if(rv[i]>=0){
      int b = dv[i]>>shift;
      pairs[bbase[b]+rv[i]] = make_int2(sv[i], dv[i]);
    }
  }
}

__global__ void k_hist2(const int2* __restrict__ pairs, int* __restrict__ deg, int n){
  int e = blockIdx.x*TPB + threadIdx.x;
  if(e<n) atomicAdd(deg + pairs[e].y, 1);
}

__global__ void k_fill2(const int2* __restrict__ pairs, int* __restrict__ offs,
                        int* __restrict__ col, int n){
  int e = blockIdx.x*TPB + threadIdx.x;
  if(e>=n) return;
  int2 p = pairs[e];
  int pos = atomicAdd(offs + p.y, 1);
  col[pos] = p.x;
}

// block = 256 threads x 8 elems = 2048
__global__ void k_scan1(const int* __restrict__ deg, int* __restrict__ offs,
                        int* __restrict__ bsum, int n){
  __shared__ int lds[TPB];
  const int tid = threadIdx.x;
  const int base = blockIdx.x*2048 + tid*8;
  int ex[8]; int s = 0;
  #pragma unroll
  for(int i=0;i<8;i++){ int idx=base+i; int x = (idx<n)? deg[idx] : 0; ex[i]=s; s+=x; }
  lds[tid] = s; __syncthreads();
  for(int off=1; off<TPB; off<<=1){
    int t = (tid>=off)? lds[tid-off] : 0;
    __syncthreads(); lds[tid] += t; __syncthreads();
  }
  int thrExcl = lds[tid] - s;
  if(tid == TPB-1) bsum[blockIdx.x] = lds[TPB-1];
  #pragma unroll
  for(int i=0;i<8;i++){ int idx=base+i; if(idx<n) offs[idx] = thrExcl + ex[i]; }
}

__global__ void k_scan2(int* __restrict__ bs, int nb){
  __shared__ int lds[TPB];
  const int tid = threadIdx.x;
  int v[4]; int s = 0;
  #pragma unroll
  for(int i=0;i<4;i++){ int idx=tid*4+i; int x = (idx<nb)? bs[idx] : 0; v[i]=s; s+=x; }
  lds[tid] = s; __syncthreads();
  for(int off=1; off<TPB; off<<=1){
    int t = (tid>=off)? lds[tid-off] : 0;
    __syncthreads(); lds[tid] += t; __syncthreads();
  }
  int thrExcl = lds[tid] - s;
  #pragma unroll
  for(int i=0;i<4;i++){ int idx=tid*4+i; if(idx<nb) bs[idx] = thrExcl + v[i]; }
}

__global__ void k_scan3(int* __restrict__ offs, const int* __restrict__ bs, int n){
  int i = blockIdx.x*TPB + threadIdx.x;
  if(i < n) offs[i] += bs[i>>11];
}

// dinv[i] = rsqrt(deg+1), written in place over the int deg array
__global__ void k_dinv(int* __restrict__ degio, int n){
  int i = blockIdx.x*TPB + threadIdx.x;
  if(i >= n) return;
  int d = degio[i];
  ((float*)degio)[i] = rsqrtf((float)d + 1.0f);
}

// ===================== dual (line-graph) GCN branch =====================
// R2 finding: k_dgath2 was 225us, 394MB fetch, applying Wg per EDGE (128
// FMA/edge, 16 redundant loop walks/node) + random dinv[s] reads.
// GCN is linear: out[d] = dinv[d]*((sum_{s in N(d)+self} dinv[s]*x[s]) @ W) + b.
// So: prescale PX = dinv*dx once; gathers become pure channel sums; the tiny
// dense W-apply happens ONCE per node in-register (channels exchanged via
// __shfl within 4/8-lane groups). No Q1/S intermediates materialized; layer-1
// output is stored pre-scaled (P2 = dinv*relu(...)) for layer 2.

// PX[n][0..3] = dinv[n] * dx[n][0..3]
__global__ void k_pscale(const float* __restrict__ dx, const float* __restrict__ dinv,
                         float4* __restrict__ PX){
  int n = blockIdx.x*TPB + threadIdx.x;
  if(n >= NDU) return;
  float4 v = *(const float4*)(dx + (size_t)n*4);
  float s = dinv[n];
  PX[n] = make_float4(v.x*s, v.y*s, v.z*s, v.w*s);
}

// layer 1: 4 lanes per node (channel-parallel gather), fused W-apply.
// P2[d][ch] = dinv[d] * relu( dinv[d]*(S1[d] . Wg1[:,ch]) + bg1[ch] ),
// S1[d][c] = sum_{s in N(d)} PX[s][c] + PX[d][c]
__global__ __launch_bounds__(TPB) void k_dual1(const float* __restrict__ PX,
                                               const float* __restrict__ Wg1,
                                               const float* __restrict__ bg1,
                                               const float* __restrict__ dinv,
                                               const int* __restrict__ offs,
                                               const int* __restrict__ col,
                                               float* __restrict__ P2){
  int t = blockIdx.x*TPB + threadIdx.x;   // over NDU*4
  if(t >= NDU*4) return;
  int d = t >> 2, c = t & 3;
  int beg = d ? offs[d-1] : 0;
  int end = offs[d];
  float acc = PX[d*4 + c];                 // self loop
  for(int j=beg; j<end; j++) acc += PX[col[j]*4 + c];
  // assemble all 4 channels of S1 in every lane of the 4-lane group
  float v0 = __shfl(acc, 0, 4), v1 = __shfl(acc, 1, 4);
  float v2 = __shfl(acc, 2, 4), v3 = __shfl(acc, 3, 4);
  float di = dinv[d];
  int ch = 2*c;
  float z0 = di*(v0*Wg1[ch]   + v1*Wg1[8+ch]   + v2*Wg1[16+ch]   + v3*Wg1[24+ch])   + bg1[ch];
  float z1 = di*(v0*Wg1[ch+1] + v1*Wg1[8+ch+1] + v2*Wg1[16+ch+1] + v3*Wg1[24+ch+1]) + bg1[ch+1];
  z0 = z0 > 0.f ? z0 : 0.f;
  z1 = z1 > 0.f ? z1 : 0.f;
  *(float2*)(P2 + (size_t)d*8 + ch) = make_float2(di*z0, di*z1);
}

// layer 2: 8 lanes per node, fused W-apply -> final Qo.
// Qo[d][ch] = dinv[d]*(S2[d] . Wg2[:,ch]) + bg2[ch],
// S2[d][c] = sum_{s in N(d)} P2[s][c] + P2[d][c]
__global__ __launch_bounds__(TPB) void k_dual2(const float* __restrict__ P2,
                                               const float* __restrict__ Wg2,
                                               const float* __restrict__ bg2,
                                               const float* __restrict__ dinv,
                                               const int* __restrict__ offs,
                                               const int* __restrict__ col,
                                               float* __restrict__ Qo){
  int t = blockIdx.x*TPB + threadIdx.x;   // over NDU*8
  if(t >= NDU*8) return;
  int d = t >> 3, c = t & 7;
  int beg = d ? offs[d-1] : 0;
  int end = offs[d];
  float acc = P2[d*8 + c];                 // self loop
  for(int j=beg; j<end; j++) acc += P2[col[j]*8 + c];
  float v[8];
  #pragma unroll
  for(int k=0;k<8;k++) v[k] = __shfl(acc, k, 8);
  float di = dinv[d];
  int ch = 2*c;
  float z0 = 0.f, z1 = 0.f;
  #pragma unroll
  for(int k=0;k<8;k++){
    z0 += v[k]*Wg2[k*16 + ch];
    z1 += v[k]*Wg2[k*16 + ch + 1];
  }
  *(float2*)(Qo + (size_t)d*16 + ch) = make_float2(di*z0 + bg2[ch], di*z1 + bg2[ch+1]);
}

// ===================== primal GAT branch =====================

// H = x @ W1 : [100000,512]x[512,64], fp32 register-tiled vector GEMM.
#define GBM 128
#define GBK 32
__global__ __launch_bounds__(TPB) void k_gemm1(const float* __restrict__ x,
                                               const float* __restrict__ W,
                                               float* __restrict__ H){
  __shared__ float xs[GBK][GBM+4];
  __shared__ float ws[GBK][64];
  const int tx = threadIdx.x;
  const int r0 = blockIdx.x*GBM;
  const int cg = tx & 15;
  const int rg = tx >> 4;

  float acc[8][4];
  #pragma unroll
  for(int i=0;i<8;i++)
    #pragma unroll
    for(int j=0;j<4;j++) acc[i][j] = 0.f;

  const int xrow = tx >> 3;
  const int xkc  = (tx & 7) * 4;
  const int wk = tx >> 4;
  const int wc = (tx & 15) * 4;

  for(int k0=0; k0<FIN; k0+=GBK){
    #pragma unroll
    for(int q=0;q<4;q++){
      int r  = xrow + q*32;
      int gr = r0 + r;
      float4 v = (gr < NP) ? *(const float4*)(x + (size_t)gr*FIN + k0 + xkc)
                           : make_float4(0.f,0.f,0.f,0.f);
      xs[xkc+0][r] = v.x; xs[xkc+1][r] = v.y;
      xs[xkc+2][r] = v.z; xs[xkc+3][r] = v.w;
    }
    #pragma unroll
    for(int q=0;q<2;q++){
      int k = wk + q*16;
      *(float4*)(&ws[k][wc]) = *(const float4*)(W + (size_t)(k0+k)*64 + wc);
    }
    __syncthreads();
    #pragma unroll 8
    for(int kk=0;kk<GBK;kk++){
      const float4 a0 = *(const float4*)(&xs[kk][rg*8]);
      const float4 a1 = *(const float4*)(&xs[kk][rg*8+4]);
      const float4 b  = *(const float4*)(&ws[kk][cg*4]);
      const float av[8] = {a0.x,a0.y,a0.z,a0.w,a1.x,a1.y,a1.z,a1.w};
      const float bv[4] = {b.x,b.y,b.z,b.w};
      #pragma unroll
      for(int i=0;i<8;i++)
        #pragma unroll
        for(int j=0;j<4;j++)
          acc[i][j] += av[i]*bv[j];
    }
    __syncthreads();
  }
  #pragma unroll
  for(int i=0;i<8;i++){
    int gr = r0 + rg*8 + i;
    if(gr < NP)
      *(float4*)(H + (size_t)gr*64 + cg*4) =
          make_float4(acc[i][0],acc[i][1],acc[i][2],acc[i][3]);
  }
}

__global__ void k_alpha(const float* __restrict__ H, const float* __restrict__ aw_s,
                        const float* __restrict__ aw_d,
                        float* __restrict__ als, float* __restrict__ ald){
  int i = blockIdx.x*TPB + threadIdx.x;     // over NP*8
  if(i >= NP*NHEAD) return;
  int n = i >> 3, h = i & 7;
  const float* hp = H + n*64 + h*8;
  float s = 0.f, d = 0.f;
  #pragma unroll
  for(int c=0;c<8;c++){ float v = hp[c]; s += v*aw_s[h*8+c]; d += v*aw_d[h*8+c]; }
  als[i] = s; ald[i] = d;
}

// GAT layer-1 gather: one wave per dst node; in-wave softmax.
__global__ __launch_bounds__(TPB) void k_agg1(const int* __restrict__ offs,
                                              const int* __restrict__ col,
                                              const float* __restrict__ als,
                                              const float* __restrict__ ald,
                                              const float* __restrict__ H,
                                              const float* __restrict__ b1,
                                              float* __restrict__ O){
  int d = (blockIdx.x*TPB + threadIdx.x) >> 6;
  int lane = threadIdx.x & 63;
  int beg = d ? offs[d-1] : 0;
  int end = offs[d];
  int h1 = lane & 7;
  float aldv = ald[d*8 + h1];
  float den = 0.f;
  for(int j0=beg; j0<end; j0+=8){
    int j = j0 + (lane>>3);
    if(j < end){
      int s = col[j];
      den += __expf(lrelu(als[s*8 + h1] + aldv));
    }
  }
  den += __shfl_xor(den, 8);
  den += __shfl_xor(den, 16);
  den += __shfl_xor(den, 32);
  den += __expf(lrelu(als[d*8 + h1] + aldv));      // self loop
  int hc = lane >> 3;
  float denc = __shfl(den, hc);
  float aldc = __shfl(aldv, hc);
  float inv = 1.f / (denc + 1e-16f);
  float acc = 0.f;
  for(int j=beg; j<end; j++){
    int s = col[j];
    float w = __expf(lrelu(als[s*8 + hc] + aldc)) * inv;
    acc += w * H[s*64 + lane];
  }
  float ws = __expf(lrelu(als[d*8 + hc] + aldc)) * inv;
  acc += ws * H[d*64 + lane];
  float v = acc + b1[lane];
  O[d*64 + lane] = v > 0.f ? v : expm1f(v);        // ELU fused
}

// G = O @ W2 ([64][16]) + layer-2 attention logits (heads=1)
__global__ void k_g(const float* __restrict__ O, const float* __restrict__ W2,
                    const float* __restrict__ asw, const float* __restrict__ adw,
                    float* __restrict__ G, float* __restrict__ as2, float* __restrict__ ad2){
  __shared__ float w2s[64*NCLS];
  for(int i=threadIdx.x; i<64*NCLS; i+=TPB) w2s[i] = W2[i];
  __syncthreads();
  int n = blockIdx.x*TPB + threadIdx.x;
  if(n >= NP) return;
  float g[16];
  #pragma unroll
  for(int c=0;c<16;c++) g[c] = 0.f;
  const float* op = O + n*64;
  #pragma unroll
  for(int k4=0;k4<64;k4+=4){
    float4 v = *(const float4*)(op + k4);
    #pragma unroll
    for(int c=0;c<16;c++){
      g[c] += v.x*w2s[(k4+0)*16+c] + v.y*w2s[(k4+1)*16+c]
            + v.z*w2s[(k4+2)*16+c] + v.w*w2s[(k4+3)*16+c];
    }
  }
  float s=0.f, t=0.f;
  #pragma unroll
  for(int c=0;c<16;c++){ s += g[c]*asw[c]; t += g[c]*adw[c]; }
  #pragma unroll
  for(int c4=0;c4<16;c4+=4)
    *(float4*)(G + n*16 + c4) = make_float4(g[c4],g[c4+1],g[c4+2],g[c4+3]);
  as2[n] = s; ad2[n] = t;
}

// GAT layer-2 gather: one wave per dst.
__global__ __launch_bounds__(TPB) void k_agg2(const int* __restrict__ offs,
                                              const int* __restrict__ col,
                                              const float* __restrict__ as2,
                                              const float* __restrict__ ad2,
                                              const float* __restrict__ G,
                                              const float* __restrict__ b2,
                                              float* __restrict__ out){
  int d = (blockIdx.x*TPB + threadIdx.x) >> 6;
  int lane = threadIdx.x & 63;
  int beg = d ? offs[d-1] : 0;
  int end = offs[d];
  float ad2d = ad2[d];
  float den = 0.f;
  for(int j0=beg; j0<end; j0+=64){
    int j = j0 + lane;
    if(j < end) den += __expf(lrelu(as2[col[j]] + ad2d));
  }
  #pragma unroll
  for(int off=32; off; off>>=1) den += __shfl_xor(den, off);
  den += __expf(lrelu(as2[d] + ad2d));             // self loop
  float inv = 1.f / (den + 1e-16f);
  int c = lane & 15, slot = lane >> 4;
  float acc = 0.f;
  for(int j0=beg; j0<end; j0+=4){
    int j = j0 + slot;
    if(j < end){
      int s = col[j];
      acc += __expf(lrelu(as2[s] + ad2d)) * inv * G[s*16 + c];
    }
  }
  acc += __shfl_xor(acc, 16);
  acc += __shfl_xor(acc, 32);
  acc += __expf(lrelu(as2[d] + ad2d)) * inv * G[d*16 + c];   // self loop
  if(lane < 16) out[d*16 + c] = acc + b2[c];
}

// ===================== launch =====================

extern "C" void kernel_launch(void* const* d_in, const int* in_sizes, int n_in,
                              void* d_out, int out_size, void* d_ws, size_t ws_size,
                              hipStream_t stream){
  const float* x    = (const float*)d_in[0];
  const int*   ei   = (const int*)  d_in[1];
  const float* dx   = (const float*)d_in[2];
  const int*   dei  = (const int*)  d_in[3];
  const float* W1   = (const float*)d_in[4];
  const float* aw1s = (const float*)d_in[5];
  const float* aw1d = (const float*)d_in[6];
  const float* b1   = (const float*)d_in[7];
  const float* W2   = (const float*)d_in[8];
  const float* aw2s = (const float*)d_in[9];
  const float* aw2d = (const float*)d_in[10];
  const float* b2   = (const float*)d_in[11];
  const float* Wg1  = (const float*)d_in[12];
  const float* bg1  = (const float*)d_in[13];
  const float* Wg2  = (const float*)d_in[14];
  const float* bg2  = (const float*)d_in[15];

  float* out = (float*)d_out;          // [NP,16]
  float* Qo  = out + NP*NCLS;          // [NDU,16]

  // workspace layout (4B words), total ~32M words = 128 MB:
  //   R[25.6M]:
  //     dual phase:   pairsD (6.4M, dies after fill2) -> PX overlays it (6.4M);
  //                   P2 at R+6.4M (12.8M)
  //     primal phase: H1(6.4M)|O1(6.4M)|G|als|ald|as2|ad2|degP|offsP|colP,
  //                   pairsP at R+19.2M (3.2M)
  //   tail: dinv/degD[1.6M] | offsD[1.6M] | colD[3.2M] | bsum[1024] | bkt[128]
  float* R     = (float*)d_ws;
  int*   degD  = (int*)(R + 25600000);      // becomes float dinv in place
  int*   offsD = degD + 1600000;
  int*   colD  = offsD + 1600000;
  int*   bsum  = colD + 3200000;            // 1024
  int*   bkt   = bsum + 1024;               // 128 bucket counters
  float* dinvF = (float*)degD;

  // dual-phase overlay
  int2*   pairsD = (int2*)R;          // 3.2M int2 (dead after k_fill2)
  float4* PX   = (float4*)R;          // 1.6M float4 = 6.4M words (after fill2)
  float*  P2   = R + 6400000;         // 12.8M words
  // primal-phase overlay (dual branch fully finished before primal kernels)
  float* H1   = R;                    // 6.4M
  float* O1   = R + 6400000;          // 6.4M
  float* G    = R + 12800000;         // 1.6M
  float* als  = R + 14400000;         // 0.8M
  float* ald  = R + 15200000;         // 0.8M
  float* as2  = R + 16000000;         // 0.1M
  float* ad2  = R + 16100000;         // 0.1M
  int*   degP = (int*)(R + 16200000); // 0.1M
  int*   offsP= degP + 100000;        // 0.1M
  int*   colP = offsP + 100000;       // 1.6M
  int2*  pairsP = (int2*)(R + 19200000); // 1.6M int2 = 3.2M words

  const int* dsrc = dei;
  const int* ddst = dei + EDU;
  const int* esrc = ei;
  const int* edst = ei + EP;

  const int SH_D = 14, NB_D = (NDU - 1 >> SH_D) + 1;   // 98
  const int SH_P = 10, NB_P = (NP  - 1 >> SH_P) + 1;   // 98

  // ---- dual CSR build (bucketed) ----
  hipMemsetAsync(degD, 0, (size_t)NDU*sizeof(int), stream);
  hipMemsetAsync(bkt,  0, BKT_MAX*sizeof(int), stream);
  k_bhist<<<(EDU+BCHUNK-1)/BCHUNK, TPB, 0, stream>>>(ddst, bkt, EDU, SH_D);
  k_bscan<<<1, TPB, 0, stream>>>(bkt, NB_D);
  k_bscat<<<(EDU+BCHUNK-1)/BCHUNK, TPB, 0, stream>>>(dsrc, ddst, bkt, pairsD, EDU, SH_D);
  k_hist2<<<EDU/TPB, TPB, 0, stream>>>(pairsD, degD, EDU);
  k_scan1<<<(NDU+2047)/2048, TPB, 0, stream>>>(degD, offsD, bsum, NDU);
  k_scan2<<<1, TPB, 0, stream>>>(bsum, (NDU+2047)/2048);
  k_scan3<<<NDU/TPB, TPB, 0, stream>>>(offsD, bsum, NDU);
  k_dinv <<<NDU/TPB, TPB, 0, stream>>>(degD, NDU);            // degD -> dinv (in place)
  k_fill2<<<EDU/TPB, TPB, 0, stream>>>(pairsD, offsD, colD, EDU);

  // ---- dual GCN (factored: prescale -> pure-sum gathers + fused W-apply) ----
  k_pscale<<<(NDU+TPB-1)/TPB, TPB, 0, stream>>>(dx, dinvF, PX);
  k_dual1 <<<NDU*4/TPB, TPB, 0, stream>>>((const float*)PX, Wg1, bg1, dinvF, offsD, colD, P2);
  k_dual2 <<<NDU*8/TPB, TPB, 0, stream>>>(P2, Wg2, bg2, dinvF, offsD, colD, Qo);

  // ---- primal CSR build (bucketed) ----
  hipMemsetAsync(degP, 0, (size_t)NP*sizeof(int), stream);
  hipMemsetAsync(bkt,  0, BKT_MAX*sizeof(int), stream);
  k_bhist<<<(EP+BCHUNK-1)/BCHUNK, TPB, 0, stream>>>(edst, bkt, EP, SH_P);
  k_bscan<<<1, TPB, 0, stream>>>(bkt, NB_P);
  k_bscat<<<(EP+BCHUNK-1)/BCHUNK, TPB, 0, stream>>>(esrc, edst, bkt, pairsP, EP, SH_P);
  k_hist2<<<EP/TPB, TPB, 0, stream>>>(pairsP, degP, EP);
  k_scan1<<<(NP+2047)/2048, TPB, 0, stream>>>(degP, offsP, bsum, NP);
  k_scan2<<<1, TPB, 0, stream>>>(bsum, (NP+2047)/2048);
  k_scan3<<<(NP+TPB-1)/TPB, TPB, 0, stream>>>(offsP, bsum, NP);
  k_fill2<<<EP/TPB, TPB, 0, stream>>>(pairsP, offsP, colP, EP);

  // ---- primal GAT ----
  k_gemm1<<<(NP+GBM-1)/GBM, TPB, 0, stream>>>(x, W1, H1);
  k_alpha<<<NP*NHEAD/TPB, TPB, 0, stream>>>(H1, aw1s, aw1d, als, ald);
  k_agg1 <<<NP/4, TPB, 0, stream>>>(offsP, colP, als, ald, H1, b1, O1);
  k_g    <<<(NP+TPB-1)/TPB, TPB, 0, stream>>>(O1, W2, aw2s, aw2d, G, as2, ad2);
  k_agg2 <<<NP/4, TPB, 0, stream>>>(offsP, colP, as2, ad2, G, b2, out);
}

// Round 4
// 1107.516 us; speedup vs baseline: 1.7036x; 1.3049x over previous
//
#include <hip/hip_runtime.h>
#include <math.h>

// Problem constants (fixed by the reference)
#define NP    100000      // primal nodes
#define EP    1600000     // primal edges
#define NDU   1600000     // dual nodes
#define EDU   3200000     // dual edges
#define FIN   512
#define NHEAD 8
#define HIDC  8
#define NCLS  16
#define NEGS  0.2f
#define TPB   256

static __device__ __forceinline__ float lrelu(float x){ return x > 0.f ? x : NEGS*x; }

// ===================== CSR build (per-dst), bucketed, atomic-free =====================
// R1: flat fill = random-line transaction bound (208MB writes). R3: bucketed
// fill STILL 168MB/210us -- global atomics execute at the cross-XCD coherence
// point and don't benefit from L2 windows. Fix: after bscat, bucket b's edges
// are contiguous in pairs[] AND its col region is the same index range, so one
// WG per bucket builds deg/offs/col/dinv entirely with LDS atomics + LDS scan.
// Replaces hist2 + scan1/2/3 + dinv + fill2 (4.8M global atomics -> 0).

#define BKT_MAX 256   // >= bucket count (196)
#define BCHUNK  2048  // edges per block in bucket kernels (8/thread)

// per-block LDS histogram of dst>>shift -> global bucket counts
__global__ void k_bhist(const int* __restrict__ dst, int* __restrict__ bcnt,
                        int n, int shift){
  __shared__ int cnt[BKT_MAX];
  for(int i=threadIdx.x;i<BKT_MAX;i+=TPB) cnt[i]=0;
  __syncthreads();
  int base = blockIdx.x*BCHUNK;
  #pragma unroll
  for(int i=0;i<8;i++){
    int e = base + i*TPB + threadIdx.x;
    if(e<n) atomicAdd(&cnt[dst[e]>>shift],1);
  }
  __syncthreads();
  for(int i=threadIdx.x;i<BKT_MAX;i+=TPB) if(cnt[i]) atomicAdd(bcnt+i, cnt[i]);
}

// exclusive scan of <=BKT_MAX bucket counts, in place (tiny; serial in LDS)
__global__ void k_bscan(int* __restrict__ bcnt, int nb){
  __shared__ int lds[BKT_MAX];
  for(int i=threadIdx.x;i<nb;i+=TPB) lds[i]=bcnt[i];
  __syncthreads();
  if(threadIdx.x==0){ int s=0; for(int i=0;i<nb;i++){ int v=lds[i]; lds[i]=s; s+=v; } }
  __syncthreads();
  for(int i=threadIdx.x;i<nb;i+=TPB) bcnt[i]=lds[i];
}

// block-local counting scatter: edges -> bucketed (src,dst) pairs.
// After this kernel, btail[b] = END of bucket b's region (= start of b+1).
__global__ __launch_bounds__(TPB) void k_bscat(const int* __restrict__ src,
                                               const int* __restrict__ dst,
                                               int* __restrict__ btail,
                                               int2* __restrict__ pairs,
                                               int n, int shift){
  __shared__ int cnt[BKT_MAX];
  __shared__ int bbase[BKT_MAX];
  for(int i=threadIdx.x;i<BKT_MAX;i+=TPB) cnt[i]=0;
  __syncthreads();
  int base = blockIdx.x*BCHUNK;
  int sv[8], dv[8], rv[8];
  #pragma unroll
  for(int i=0;i<8;i++){
    int e = base + i*TPB + threadIdx.x;
    if(e<n){ sv[i]=src[e]; dv[i]=dst[e]; rv[i]=atomicAdd(&cnt[dv[i]>>shift],1); }
    else rv[i]=-1;
  }
  __syncthreads();
  for(int i=threadIdx.x;i<BKT_MAX;i+=TPB){
    int c = cnt[i];
    bbase[i] = c ? atomicAdd(btail+i, c) : 0;
  }
  __syncthreads();
  #pragma unroll
  for(int i=0;i<8;i++){
    if(rv[i]>=0){
      int b = dv[i]>>shift;
      pairs[bbase[b]+rv[i]] = make_int2(sv[i], dv[i]);
    }
  }
}

// one WG per bucket: LDS hist -> LDS scan -> offs/dinv writeback -> LDS-ranked
// col scatter. Bucket b's edges = pairs[ebeg..eend), its col region = same
// range (pairs index == col index globally), so colbase = ebeg.
// Dynamic LDS: (1<<shift) ints.
__global__ __launch_bounds__(TPB) void k_csr(const int2* __restrict__ pairs,
                                             const int* __restrict__ btail,
                                             int* __restrict__ offs,
                                             float* __restrict__ dinv,
                                             int* __restrict__ col,
                                             int nnodes, int shift){
  extern __shared__ int ldeg[];
  __shared__ int ttmp[TPB];
  const int b    = blockIdx.x;
  const int tid  = threadIdx.x;
  const int ebeg = b ? btail[b-1] : 0;
  const int eend = btail[b];
  const int node0 = b << shift;
  const int W     = 1 << shift;
  const int PW    = W / TPB;           // elems per thread in scan (32 dual, 2 primal)

  for(int i=tid;i<W;i+=TPB) ldeg[i]=0;
  __syncthreads();
  for(int e=ebeg+tid; e<eend; e+=TPB)
    atomicAdd(&ldeg[pairs[e].y - node0], 1);
  __syncthreads();

  // block scan over W elements
  const int base = tid*PW;
  int s = 0;
  for(int i=0;i<PW;i++) s += ldeg[base+i];
  ttmp[tid] = s; __syncthreads();
  for(int off=1; off<TPB; off<<=1){
    int t = (tid>=off)? ttmp[tid-off] : 0;
    __syncthreads(); ttmp[tid] += t; __syncthreads();
  }
  int run = ttmp[tid] - s;             // thread-exclusive prefix (local edges)

  // writeback: offs (global inclusive prefix), dinv, and ldeg -> global excl start
  for(int i=0;i<PW;i++){
    int d  = base + i;
    int g  = node0 + d;
    int dg = ldeg[d];
    if(g < nnodes){
      offs[g] = ebeg + run + dg;                  // inclusive
      dinv[g] = rsqrtf((float)dg + 1.0f);
    }
    ldeg[d] = ebeg + run;                         // exclusive start (global col idx)
    run += dg;
  }
  __syncthreads();

  // col scatter with LDS-atomic rank; writes confined to [ebeg,eend)
  for(int e=ebeg+tid; e<eend; e+=TPB){
    int2 p = pairs[e];
    int pos = atomicAdd(&ldeg[p.y - node0], 1);
    col[pos] = p.x;
  }
}

// ===================== dual (line-graph) GCN branch =====================
// R2: GCN is linear -> factor W out of the gather. PX = dinv*dx prescaled;
// gathers are pure channel sums; tiny dense W-apply once per node in-register
// (channels exchanged via __shfl in 4/8-lane groups). Layer-1 output stored
// pre-scaled (P2 = dinv*relu(...)) for layer 2.

// PX[n][0..3] = dinv[n] * dx[n][0..3]
__global__ void k_pscale(const float* __restrict__ dx, const float* __restrict__ dinv,
                         float4* __restrict__ PX){
  int n = blockIdx.x*TPB + threadIdx.x;
  if(n >= NDU) return;
  float4 v = *(const float4*)(dx + (size_t)n*4);
  float s = dinv[n];
  PX[n] = make_float4(v.x*s, v.y*s, v.z*s, v.w*s);
}

// layer 1: 4 lanes per node (channel-parallel gather), fused W-apply.
__global__ __launch_bounds__(TPB) void k_dual1(const float* __restrict__ PX,
                                               const float* __restrict__ Wg1,
                                               const float* __restrict__ bg1,
                                               const float* __restrict__ dinv,
                                               const int* __restrict__ offs,
                                               const int* __restrict__ col,
                                               float* __restrict__ P2){
  int t = blockIdx.x*TPB + threadIdx.x;   // over NDU*4
  if(t >= NDU*4) return;
  int d = t >> 2, c = t & 3;
  int beg = d ? offs[d-1] : 0;
  int end = offs[d];
  float acc = PX[d*4 + c];                 // self loop
  for(int j=beg; j<end; j++) acc += PX[col[j]*4 + c];
  float v0 = __shfl(acc, 0, 4), v1 = __shfl(acc, 1, 4);
  float v2 = __shfl(acc, 2, 4), v3 = __shfl(acc, 3, 4);
  float di = dinv[d];
  int ch = 2*c;
  float z0 = di*(v0*Wg1[ch]   + v1*Wg1[8+ch]   + v2*Wg1[16+ch]   + v3*Wg1[24+ch])   + bg1[ch];
  float z1 = di*(v0*Wg1[ch+1] + v1*Wg1[8+ch+1] + v2*Wg1[16+ch+1] + v3*Wg1[24+ch+1]) + bg1[ch+1];
  z0 = z0 > 0.f ? z0 : 0.f;
  z1 = z1 > 0.f ? z1 : 0.f;
  *(float2*)(P2 + (size_t)d*8 + ch) = make_float2(di*z0, di*z1);
}

// layer 2: 8 lanes per node, fused W-apply -> final Qo.
__global__ __launch_bounds__(TPB) void k_dual2(const float* __restrict__ P2,
                                               const float* __restrict__ Wg2,
                                               const float* __restrict__ bg2,
                                               const float* __restrict__ dinv,
                                               const int* __restrict__ offs,
                                               const int* __restrict__ col,
                                               float* __restrict__ Qo){
  int t = blockIdx.x*TPB + threadIdx.x;   // over NDU*8
  if(t >= NDU*8) return;
  int d = t >> 3, c = t & 7;
  int beg = d ? offs[d-1] : 0;
  int end = offs[d];
  float acc = P2[d*8 + c];                 // self loop
  for(int j=beg; j<end; j++) acc += P2[col[j]*8 + c];
  float v[8];
  #pragma unroll
  for(int k=0;k<8;k++) v[k] = __shfl(acc, k, 8);
  float di = dinv[d];
  int ch = 2*c;
  float z0 = 0.f, z1 = 0.f;
  #pragma unroll
  for(int k=0;k<8;k++){
    z0 += v[k]*Wg2[k*16 + ch];
    z1 += v[k]*Wg2[k*16 + ch + 1];
  }
  *(float2*)(Qo + (size_t)d*16 + ch) = make_float2(di*z0 + bg2[ch], di*z1 + bg2[ch+1]);
}

// ===================== primal GAT branch =====================

// H = x @ W1 : [100000,512]x[512,64], fp32 register-tiled vector GEMM.
#define GBM 128
#define GBK 32
__global__ __launch_bounds__(TPB) void k_gemm1(const float* __restrict__ x,
                                               const float* __restrict__ W,
                                               float* __restrict__ H){
  __shared__ float xs[GBK][GBM+4];
  __shared__ float ws[GBK][64];
  const int tx = threadIdx.x;
  const int r0 = blockIdx.x*GBM;
  const int cg = tx & 15;
  const int rg = tx >> 4;

  float acc[8][4];
  #pragma unroll
  for(int i=0;i<8;i++)
    #pragma unroll
    for(int j=0;j<4;j++) acc[i][j] = 0.f;

  const int xrow = tx >> 3;
  const int xkc  = (tx & 7) * 4;
  const int wk = tx >> 4;
  const int wc = (tx & 15) * 4;

  for(int k0=0; k0<FIN; k0+=GBK){
    #pragma unroll
    for(int q=0;q<4;q++){
      int r  = xrow + q*32;
      int gr = r0 + r;
      float4 v = (gr < NP) ? *(const float4*)(x + (size_t)gr*FIN + k0 + xkc)
                           : make_float4(0.f,0.f,0.f,0.f);
      xs[xkc+0][r] = v.x; xs[xkc+1][r] = v.y;
      xs[xkc+2][r] = v.z; xs[xkc+3][r] = v.w;
    }
    #pragma unroll
    for(int q=0;q<2;q++){
      int k = wk + q*16;
      *(float4*)(&ws[k][wc]) = *(const float4*)(W + (size_t)(k0+k)*64 + wc);
    }
    __syncthreads();
    #pragma unroll 8
    for(int kk=0;kk<GBK;kk++){
      const float4 a0 = *(const float4*)(&xs[kk][rg*8]);
      const float4 a1 = *(const float4*)(&xs[kk][rg*8+4]);
      const float4 b  = *(const float4*)(&ws[kk][cg*4]);
      const float av[8] = {a0.x,a0.y,a0.z,a0.w,a1.x,a1.y,a1.z,a1.w};
      const float bv[4] = {b.x,b.y,b.z,b.w};
      #pragma unroll
      for(int i=0;i<8;i++)
        #pragma unroll
        for(int j=0;j<4;j++)
          acc[i][j] += av[i]*bv[j];
    }
    __syncthreads();
  }
  #pragma unroll
  for(int i=0;i<8;i++){
    int gr = r0 + rg*8 + i;
    if(gr < NP)
      *(float4*)(H + (size_t)gr*64 + cg*4) =
          make_float4(acc[i][0],acc[i][1],acc[i][2],acc[i][3]);
  }
}

__global__ void k_alpha(const float* __restrict__ H, const float* __restrict__ aw_s,
                        const float* __restrict__ aw_d,
                        float* __restrict__ als, float* __restrict__ ald){
  int i = blockIdx.x*TPB + threadIdx.x;     // over NP*8
  if(i >= NP*NHEAD) return;
  int n = i >> 3, h = i & 7;
  const float* hp = H + n*64 + h*8;
  float s = 0.f, d = 0.f;
  #pragma unroll
  for(int c=0;c<8;c++){ float v = hp[c]; s += v*aw_s[h*8+c]; d += v*aw_d[h*8+c]; }
  als[i] = s; ald[i] = d;
}

// GAT layer-1 gather: one wave per dst node; in-wave softmax.
__global__ __launch_bounds__(TPB) void k_agg1(const int* __restrict__ offs,
                                              const int* __restrict__ col,
                                              const float* __restrict__ als,
                                              const float* __restrict__ ald,
                                              const float* __restrict__ H,
                                              const float* __restrict__ b1,
                                              float* __restrict__ O){
  int d = (blockIdx.x*TPB + threadIdx.x) >> 6;
  int lane = threadIdx.x & 63;
  int beg = d ? offs[d-1] : 0;
  int end = offs[d];
  int h1 = lane & 7;
  float aldv = ald[d*8 + h1];
  float den = 0.f;
  for(int j0=beg; j0<end; j0+=8){
    int j = j0 + (lane>>3);
    if(j < end){
      int s = col[j];
      den += __expf(lrelu(als[s*8 + h1] + aldv));
    }
  }
  den += __shfl_xor(den, 8);
  den += __shfl_xor(den, 16);
  den += __shfl_xor(den, 32);
  den += __expf(lrelu(als[d*8 + h1] + aldv));      // self loop
  int hc = lane >> 3;
  float denc = __shfl(den, hc);
  float aldc = __shfl(aldv, hc);
  float inv = 1.f / (denc + 1e-16f);
  float acc = 0.f;
  for(int j=beg; j<end; j++){
    int s = col[j];
    float w = __expf(lrelu(als[s*8 + hc] + aldc)) * inv;
    acc += w * H[s*64 + lane];
  }
  float ws = __expf(lrelu(als[d*8 + hc] + aldc)) * inv;
  acc += ws * H[d*64 + lane];
  float v = acc + b1[lane];
  O[d*64 + lane] = v > 0.f ? v : expm1f(v);        // ELU fused
}

// G = O @ W2 ([64][16]) + layer-2 attention logits (heads=1)
__global__ void k_g(const float* __restrict__ O, const float* __restrict__ W2,
                    const float* __restrict__ asw, const float* __restrict__ adw,
                    float* __restrict__ G, float* __restrict__ as2, float* __restrict__ ad2){
  __shared__ float w2s[64*NCLS];
  for(int i=threadIdx.x; i<64*NCLS; i+=TPB) w2s[i] = W2[i];
  __syncthreads();
  int n = blockIdx.x*TPB + threadIdx.x;
  if(n >= NP) return;
  float g[16];
  #pragma unroll
  for(int c=0;c<16;c++) g[c] = 0.f;
  const float* op = O + n*64;
  #pragma unroll
  for(int k4=0;k4<64;k4+=4){
    float4 v = *(const float4*)(op + k4);
    #pragma unroll
    for(int c=0;c<16;c++){
      g[c] += v.x*w2s[(k4+0)*16+c] + v.y*w2s[(k4+1)*16+c]
            + v.z*w2s[(k4+2)*16+c] + v.w*w2s[(k4+3)*16+c];
    }
  }
  float s=0.f, t=0.f;
  #pragma unroll
  for(int c=0;c<16;c++){ s += g[c]*asw[c]; t += g[c]*adw[c]; }
  #pragma unroll
  for(int c4=0;c4<16;c4+=4)
    *(float4*)(G + n*16 + c4) = make_float4(g[c4],g[c4+1],g[c4+2],g[c4+3]);
  as2[n] = s; ad2[n] = t;
}

// GAT layer-2 gather: one wave per dst.
__global__ __launch_bounds__(TPB) void k_agg2(const int* __restrict__ offs,
                                              const int* __restrict__ col,
                                              const float* __restrict__ as2,
                                              const float* __restrict__ ad2,
                                              const float* __restrict__ G,
                                              const float* __restrict__ b2,
                                              float* __restrict__ out){
  int d = (blockIdx.x*TPB + threadIdx.x) >> 6;
  int lane = threadIdx.x & 63;
  int beg = d ? offs[d-1] : 0;
  int end = offs[d];
  float ad2d = ad2[d];
  float den = 0.f;
  for(int j0=beg; j0<end; j0+=64){
    int j = j0 + lane;
    if(j < end) den += __expf(lrelu(as2[col[j]] + ad2d));
  }
  #pragma unroll
  for(int off=32; off; off>>=1) den += __shfl_xor(den, off);
  den += __expf(lrelu(as2[d] + ad2d));             // self loop
  float inv = 1.f / (den + 1e-16f);
  int c = lane & 15, slot = lane >> 4;
  float acc = 0.f;
  for(int j0=beg; j0<end; j0+=4){
    int j = j0 + slot;
    if(j < end){
      int s = col[j];
      acc += __expf(lrelu(as2[s] + ad2d)) * inv * G[s*16 + c];
    }
  }
  acc += __shfl_xor(acc, 16);
  acc += __shfl_xor(acc, 32);
  acc += __expf(lrelu(as2[d] + ad2d)) * inv * G[d*16 + c];   // self loop
  if(lane < 16) out[d*16 + c] = acc + b2[c];
}

// ===================== launch =====================

extern "C" void kernel_launch(void* const* d_in, const int* in_sizes, int n_in,
                              void* d_out, int out_size, void* d_ws, size_t ws_size,
                              hipStream_t stream){
  const float* x    = (const float*)d_in[0];
  const int*   ei   = (const int*)  d_in[1];
  const float* dx   = (const float*)d_in[2];
  const int*   dei  = (const int*)  d_in[3];
  const float* W1   = (const float*)d_in[4];
  const float* aw1s = (const float*)d_in[5];
  const float* aw1d = (const float*)d_in[6];
  const float* b1   = (const float*)d_in[7];
  const float* W2   = (const float*)d_in[8];
  const float* aw2s = (const float*)d_in[9];
  const float* aw2d = (const float*)d_in[10];
  const float* b2   = (const float*)d_in[11];
  const float* Wg1  = (const float*)d_in[12];
  const float* bg1  = (const float*)d_in[13];
  const float* Wg2  = (const float*)d_in[14];
  const float* bg2  = (const float*)d_in[15];

  float* out = (float*)d_out;          // [NP,16]
  float* Qo  = out + NP*NCLS;          // [NDU,16]

  // workspace layout (4B words), total ~32M words = 128 MB:
  //   R[25.6M]:
  //     dual phase:   pairsD [0,6.4M) (dead after k_csr) -> PX overlays it;
  //                   P2 [6.4M,19.2M)
  //     primal phase: H1[0,6.4M)|O1[6.4,12.8)|G[12.8,14.4)|als|ald|as2|ad2|
  //                   dinvP[16.2,16.3)|offsP[16.3,16.4)|colP[16.4,18.0)|
  //                   pairsP[19.2,22.4)
  //   tail: dinvD[1.6M] | offsD[1.6M] | colD[3.2M] | bkt[256]
  float* R     = (float*)d_ws;
  float* dinvD = R + 25600000;
  int*   offsD = (int*)(dinvD + 1600000);
  int*   colD  = offsD + 1600000;
  int*   bkt   = colD + 3200000;            // 256 bucket counters

  // dual-phase overlay
  int2*   pairsD = (int2*)R;          // 3.2M int2 (dead after k_csr)
  float4* PX   = (float4*)R;          // 1.6M float4 (after k_csr)
  float*  P2   = R + 6400000;         // 12.8M words
  // primal-phase overlay (dual branch fully finished before primal kernels)
  float* H1   = R;                    // 6.4M
  float* O1   = R + 6400000;          // 6.4M
  float* G    = R + 12800000;         // 1.6M
  float* als  = R + 14400000;         // 0.8M
  float* ald  = R + 15200000;         // 0.8M
  float* as2  = R + 16000000;         // 0.1M
  float* ad2  = R + 16100000;         // 0.1M
  float* dinvP= R + 16200000;         // 0.1M (scratch; GAT doesn't use dinv)
  int*   offsP= (int*)(R + 16300000); // 0.1M
  int*   colP = offsP + 100000;       // 1.6M
  int2*  pairsP = (int2*)(R + 19200000); // 1.6M int2 = 3.2M words

  const int* dsrc = dei;
  const int* ddst = dei + EDU;
  const int* esrc = ei;
  const int* edst = ei + EP;

  // dual: 8192-node windows (32KB LDS); primal: 512-node windows (2KB LDS)
  const int SH_D = 13, NB_D = ((NDU - 1) >> SH_D) + 1;   // 196
  const int SH_P = 9,  NB_P = ((NP  - 1) >> SH_P) + 1;   // 196

  // ---- dual CSR build (bucketed, atomic-free CSR) ----
  hipMemsetAsync(bkt, 0, BKT_MAX*sizeof(int), stream);
  k_bhist<<<(EDU+BCHUNK-1)/BCHUNK, TPB, 0, stream>>>(ddst, bkt, EDU, SH_D);
  k_bscan<<<1, TPB, 0, stream>>>(bkt, NB_D);
  k_bscat<<<(EDU+BCHUNK-1)/BCHUNK, TPB, 0, stream>>>(dsrc, ddst, bkt, pairsD, EDU, SH_D);
  k_csr  <<<NB_D, TPB, (1<<SH_D)*sizeof(int), stream>>>(pairsD, bkt, offsD, dinvD, colD, NDU, SH_D);

  // ---- dual GCN (factored: prescale -> pure-sum gathers + fused W-apply) ----
  k_pscale<<<(NDU+TPB-1)/TPB, TPB, 0, stream>>>(dx, dinvD, PX);
  k_dual1 <<<NDU*4/TPB, TPB, 0, stream>>>((const float*)PX, Wg1, bg1, dinvD, offsD, colD, P2);
  k_dual2 <<<NDU*8/TPB, TPB, 0, stream>>>(P2, Wg2, bg2, dinvD, offsD, colD, Qo);

  // ---- primal CSR build (bucketed, atomic-free CSR) ----
  hipMemsetAsync(bkt, 0, BKT_MAX*sizeof(int), stream);
  k_bhist<<<(EP+BCHUNK-1)/BCHUNK, TPB, 0, stream>>>(edst, bkt, EP, SH_P);
  k_bscan<<<1, TPB, 0, stream>>>(bkt, NB_P);
  k_bscat<<<(EP+BCHUNK-1)/BCHUNK, TPB, 0, stream>>>(esrc, edst, bkt, pairsP, EP, SH_P);
  k_csr  <<<NB_P, TPB, (1<<SH_P)*sizeof(int), stream>>>(pairsP, bkt, offsP, dinvP, colP, NP, SH_P);

  // ---- primal GAT ----
  k_gemm1<<<(NP+GBM-1)/GBM, TPB, 0, stream>>>(x, W1, H1);
  k_alpha<<<NP*NHEAD/TPB, TPB, 0, stream>>>(H1, aw1s, aw1d, als, ald);
  k_agg1 <<<NP/4, TPB, 0, stream>>>(offsP, colP, als, ald, H1, b1, O1);
  k_g    <<<(NP+TPB-1)/TPB, TPB, 0, stream>>>(O1, W2, aw2s, aw2d, G, as2, ad2);
  k_agg2 <<<NP/4, TPB, 0, stream>>>(offsP, colP, as2, ad2, G, b2, out);
}

// Round 5
// 1073.667 us; speedup vs baseline: 1.7573x; 1.0315x over previous
//
#include <hip/hip_runtime.h>
#include <math.h>

// Problem constants (fixed by the reference)
#define NP    100000      // primal nodes
#define EP    1600000     // primal edges
#define NDU   1600000     // dual nodes
#define EDU   3200000     // dual edges
#define FIN   512
#define NHEAD 8
#define HIDC  8
#define NCLS  16
#define NEGS  0.2f
#define TPB   256

static __device__ __forceinline__ float lrelu(float x){ return x > 0.f ? x : NEGS*x; }

// ===================== CSR build (per-dst), bucketed, atomic-free =====================
// R1: flat fill = random-line transaction bound. R3: global atomics don't
// benefit from L2 windows (cross-XCD coherence point). R4 design: bscat makes
// bucket b's edges contiguous in pairs[]; k_csr builds deg/offs/col/dinv per
// bucket with LDS atomics + LDS scan only.

#define BKT_MAX 256   // >= bucket count (196)
#define BCHUNK  2048  // edges per block in bucket kernels (8/thread)

__global__ void k_bhist(const int* __restrict__ dst, int* __restrict__ bcnt,
                        int n, int shift){
  __shared__ int cnt[BKT_MAX];
  for(int i=threadIdx.x;i<BKT_MAX;i+=TPB) cnt[i]=0;
  __syncthreads();
  int base = blockIdx.x*BCHUNK;
  #pragma unroll
  for(int i=0;i<8;i++){
    int e = base + i*TPB + threadIdx.x;
    if(e<n) atomicAdd(&cnt[dst[e]>>shift],1);
  }
  __syncthreads();
  for(int i=threadIdx.x;i<BKT_MAX;i+=TPB) if(cnt[i]) atomicAdd(bcnt+i, cnt[i]);
}

__global__ void k_bscan(int* __restrict__ bcnt, int nb){
  __shared__ int lds[BKT_MAX];
  for(int i=threadIdx.x;i<nb;i+=TPB) lds[i]=bcnt[i];
  __syncthreads();
  if(threadIdx.x==0){ int s=0; for(int i=0;i<nb;i++){ int v=lds[i]; lds[i]=s; s+=v; } }
  __syncthreads();
  for(int i=threadIdx.x;i<nb;i+=TPB) bcnt[i]=lds[i];
}

// block-local counting scatter: edges -> bucketed (src,dst) pairs.
// After this kernel, btail[b] = END of bucket b's region.
__global__ __launch_bounds__(TPB) void k_bscat(const int* __restrict__ src,
                                               const int* __restrict__ dst,
                                               int* __restrict__ btail,
                                               int2* __restrict__ pairs,
                                               int n, int shift){
  __shared__ int cnt[BKT_MAX];
  __shared__ int bbase[BKT_MAX];
  for(int i=threadIdx.x;i<BKT_MAX;i+=TPB) cnt[i]=0;
  __syncthreads();
  int base = blockIdx.x*BCHUNK;
  int sv[8], dv[8], rv[8];
  #pragma unroll
  for(int i=0;i<8;i++){
    int e = base + i*TPB + threadIdx.x;
    if(e<n){ sv[i]=src[e]; dv[i]=dst[e]; rv[i]=atomicAdd(&cnt[dv[i]>>shift],1); }
    else rv[i]=-1;
  }
  __syncthreads();
  for(int i=threadIdx.x;i<BKT_MAX;i+=TPB){
    int c = cnt[i];
    bbase[i] = c ? atomicAdd(btail+i, c) : 0;
  }
  __syncthreads();
  #pragma unroll
  for(int i=0;i<8;i++){
    if(rv[i]>=0){
      int b = dv[i]>>shift;
      pairs[bbase[b]+rv[i]] = make_int2(sv[i], dv[i]);
    }
  }
}

// one WG per bucket: LDS hist -> LDS scan -> offs/dinv writeback -> LDS-ranked
// col scatter. Dynamic LDS: (1<<shift) ints.
__global__ __launch_bounds__(TPB) void k_csr(const int2* __restrict__ pairs,
                                             const int* __restrict__ btail,
                                             int* __restrict__ offs,
                                             float* __restrict__ dinv,
                                             int* __restrict__ col,
                                             int nnodes, int shift){
  extern __shared__ int ldeg[];
  __shared__ int ttmp[TPB];
  const int b    = blockIdx.x;
  const int tid  = threadIdx.x;
  const int ebeg = b ? btail[b-1] : 0;
  const int eend = btail[b];
  const int node0 = b << shift;
  const int W     = 1 << shift;
  const int PW    = W / TPB;

  for(int i=tid;i<W;i+=TPB) ldeg[i]=0;
  __syncthreads();
  for(int e=ebeg+tid; e<eend; e+=TPB)
    atomicAdd(&ldeg[pairs[e].y - node0], 1);
  __syncthreads();

  const int base = tid*PW;
  int s = 0;
  for(int i=0;i<PW;i++) s += ldeg[base+i];
  ttmp[tid] = s; __syncthreads();
  for(int off=1; off<TPB; off<<=1){
    int t = (tid>=off)? ttmp[tid-off] : 0;
    __syncthreads(); ttmp[tid] += t; __syncthreads();
  }
  int run = ttmp[tid] - s;

  for(int i=0;i<PW;i++){
    int d  = base + i;
    int g  = node0 + d;
    int dg = ldeg[d];
    if(g < nnodes){
      offs[g] = ebeg + run + dg;                  // inclusive
      dinv[g] = rsqrtf((float)dg + 1.0f);
    }
    ldeg[d] = ebeg + run;                         // exclusive start (global col idx)
    run += dg;
  }
  __syncthreads();

  for(int e=ebeg+tid; e<eend; e+=TPB){
    int2 p = pairs[e];
    int pos = atomicAdd(&ldeg[p.y - node0], 1);
    col[pos] = p.x;
  }
}

// ===================== dual (line-graph) GCN branch =====================
// R2: GCN is linear -> factor W out of the gather. PX = dinv*dx prescaled;
// gathers are pure channel sums; dense W-apply once per node in-register.

__global__ void k_pscale(const float* __restrict__ dx, const float* __restrict__ dinv,
                         float4* __restrict__ PX){
  int n = blockIdx.x*TPB + threadIdx.x;
  if(n >= NDU) return;
  float4 v = *(const float4*)(dx + (size_t)n*4);
  float s = dinv[n];
  PX[n] = make_float4(v.x*s, v.y*s, v.z*s, v.w*s);
}

// layer 1: 4 lanes per node (channel-parallel gather), fused W-apply.
__global__ __launch_bounds__(TPB) void k_dual1(const float* __restrict__ PX,
                                               const float* __restrict__ Wg1,
                                               const float* __restrict__ bg1,
                                               const float* __restrict__ dinv,
                                               const int* __restrict__ offs,
                                               const int* __restrict__ col,
                                               float* __restrict__ P2){
  int t = blockIdx.x*TPB + threadIdx.x;   // over NDU*4
  if(t >= NDU*4) return;
  int d = t >> 2, c = t & 3;
  int beg = d ? offs[d-1] : 0;
  int end = offs[d];
  float acc = PX[d*4 + c];                 // self loop
  for(int j=beg; j<end; j++) acc += PX[col[j]*4 + c];
  float v0 = __shfl(acc, 0, 4), v1 = __shfl(acc, 1, 4);
  float v2 = __shfl(acc, 2, 4), v3 = __shfl(acc, 3, 4);
  float di = dinv[d];
  int ch = 2*c;
  float z0 = di*(v0*Wg1[ch]   + v1*Wg1[8+ch]   + v2*Wg1[16+ch]   + v3*Wg1[24+ch])   + bg1[ch];
  float z1 = di*(v0*Wg1[ch+1] + v1*Wg1[8+ch+1] + v2*Wg1[16+ch+1] + v3*Wg1[24+ch+1]) + bg1[ch+1];
  z0 = z0 > 0.f ? z0 : 0.f;
  z1 = z1 > 0.f ? z1 : 0.f;
  *(float2*)(P2 + (size_t)d*8 + ch) = make_float2(di*z0, di*z1);
}

// layer 2: 8 lanes per node, fused W-apply -> final Qo.
__global__ __launch_bounds__(TPB) void k_dual2(const float* __restrict__ P2,
                                               const float* __restrict__ Wg2,
                                               const float* __restrict__ bg2,
                                               const float* __restrict__ dinv,
                                               const int* __restrict__ offs,
                                               const int* __restrict__ col,
                                               float* __restrict__ Qo){
  int t = blockIdx.x*TPB + threadIdx.x;   // over NDU*8
  if(t >= NDU*8) return;
  int d = t >> 3, c = t & 7;
  int beg = d ? offs[d-1] : 0;
  int end = offs[d];
  float acc = P2[d*8 + c];                 // self loop
  for(int j=beg; j<end; j++) acc += P2[col[j]*8 + c];
  float v[8];
  #pragma unroll
  for(int k=0;k<8;k++) v[k] = __shfl(acc, k, 8);
  float di = dinv[d];
  int ch = 2*c;
  float z0 = 0.f, z1 = 0.f;
  #pragma unroll
  for(int k=0;k<8;k++){
    z0 += v[k]*Wg2[k*16 + ch];
    z1 += v[k]*Wg2[k*16 + ch + 1];
  }
  *(float2*)(Qo + (size_t)d*16 + ch) = make_float2(di*z0 + bg2[ch], di*z1 + bg2[ch+1]);
}

// ===================== primal GAT branch =====================

// H = x @ W1 : [100000,512]x[512,64], fp32 register-tiled vector GEMM.
#define GBM 128
#define GBK 32
__global__ __launch_bounds__(TPB) void k_gemm1(const float* __restrict__ x,
                                               const float* __restrict__ W,
                                               float* __restrict__ H){
  __shared__ float xs[GBK][GBM+4];
  __shared__ float ws[GBK][64];
  const int tx = threadIdx.x;
  const int r0 = blockIdx.x*GBM;
  const int cg = tx & 15;
  const int rg = tx >> 4;

  float acc[8][4];
  #pragma unroll
  for(int i=0;i<8;i++)
    #pragma unroll
    for(int j=0;j<4;j++) acc[i][j] = 0.f;

  const int xrow = tx >> 3;
  const int xkc  = (tx & 7) * 4;
  const int wk = tx >> 4;
  const int wc = (tx & 15) * 4;

  for(int k0=0; k0<FIN; k0+=GBK){
    #pragma unroll
    for(int q=0;q<4;q++){
      int r  = xrow + q*32;
      int gr = r0 + r;
      float4 v = (gr < NP) ? *(const float4*)(x + (size_t)gr*FIN + k0 + xkc)
                           : make_float4(0.f,0.f,0.f,0.f);
      xs[xkc+0][r] = v.x; xs[xkc+1][r] = v.y;
      xs[xkc+2][r] = v.z; xs[xkc+3][r] = v.w;
    }
    #pragma unroll
    for(int q=0;q<2;q++){
      int k = wk + q*16;
      *(float4*)(&ws[k][wc]) = *(const float4*)(W + (size_t)(k0+k)*64 + wc);
    }
    __syncthreads();
    #pragma unroll 8
    for(int kk=0;kk<GBK;kk++){
      const float4 a0 = *(const float4*)(&xs[kk][rg*8]);
      const float4 a1 = *(const float4*)(&xs[kk][rg*8+4]);
      const float4 b  = *(const float4*)(&ws[kk][cg*4]);
      const float av[8] = {a0.x,a0.y,a0.z,a0.w,a1.x,a1.y,a1.z,a1.w};
      const float bv[4] = {b.x,b.y,b.z,b.w};
      #pragma unroll
      for(int i=0;i<8;i++)
        #pragma unroll
        for(int j=0;j<4;j++)
          acc[i][j] += av[i]*bv[j];
    }
    __syncthreads();
  }
  #pragma unroll
  for(int i=0;i<8;i++){
    int gr = r0 + rg*8 + i;
    if(gr < NP)
      *(float4*)(H + (size_t)gr*64 + cg*4) =
          make_float4(acc[i][0],acc[i][1],acc[i][2],acc[i][3]);
  }
}

__global__ void k_alpha(const float* __restrict__ H, const float* __restrict__ aw_s,
                        const float* __restrict__ aw_d,
                        float* __restrict__ als, float* __restrict__ ald){
  int i = blockIdx.x*TPB + threadIdx.x;     // over NP*8
  if(i >= NP*NHEAD) return;
  int n = i >> 3, h = i & 7;
  const float* hp = H + n*64 + h*8;
  float s = 0.f, d = 0.f;
  #pragma unroll
  for(int c=0;c<8;c++){ float v = hp[c]; s += v*aw_s[h*8+c]; d += v*aw_d[h*8+c]; }
  als[i] = s; ald[i] = d;
}

// GAT layer-1 gather: one wave per dst node, SINGLE-PASS softmax.
// R4 finding: two-pass (den walk, then acc walk) re-read als per edge and
// recomputed exps (272MB fetch, 35% VALU, latency-chain bound). Since
// out = (sum_s e_s*H[s]) / (sum_s e_s), accumulate both in ONE edge walk and
// divide at the end. den needs no cross-lane reduce: all 8 lanes of a head
// accumulate the identical w stream. Logits bounded (~e^6), fp32-safe.
__global__ __launch_bounds__(TPB) void k_agg1(const int* __restrict__ offs,
                                              const int* __restrict__ col,
                                              const float* __restrict__ als,
                                              const float* __restrict__ ald,
                                              const float* __restrict__ H,
                                              const float* __restrict__ b1,
                                              float* __restrict__ O){
  int d = (blockIdx.x*TPB + threadIdx.x) >> 6;   // wave per dst
  int lane = threadIdx.x & 63;
  int hc = lane >> 3;                            // head for this channel
  int beg = d ? offs[d-1] : 0;
  int end = offs[d];
  float aldc = ald[d*8 + hc];
  float den = 0.f, acc = 0.f;
  for(int j=beg; j<end; j++){
    int s = col[j];
    float w = __expf(lrelu(als[s*8 + hc] + aldc));
    den += w;
    acc += w * H[s*64 + lane];
  }
  float ws = __expf(lrelu(als[d*8 + hc] + aldc));  // self loop
  den += ws;
  acc += ws * H[d*64 + lane];
  float v = acc / (den + 1e-16f) + b1[lane];
  O[d*64 + lane] = v > 0.f ? v : expm1f(v);        // ELU fused
}

// G = O @ W2 ([64][16]) + layer-2 attention logits (heads=1)
__global__ void k_g(const float* __restrict__ O, const float* __restrict__ W2,
                    const float* __restrict__ asw, const float* __restrict__ adw,
                    float* __restrict__ G, float* __restrict__ as2, float* __restrict__ ad2){
  __shared__ float w2s[64*NCLS];
  for(int i=threadIdx.x; i<64*NCLS; i+=TPB) w2s[i] = W2[i];
  __syncthreads();
  int n = blockIdx.x*TPB + threadIdx.x;
  if(n >= NP) return;
  float g[16];
  #pragma unroll
  for(int c=0;c<16;c++) g[c] = 0.f;
  const float* op = O + n*64;
  #pragma unroll
  for(int k4=0;k4<64;k4+=4){
    float4 v = *(const float4*)(op + k4);
    #pragma unroll
    for(int c=0;c<16;c++){
      g[c] += v.x*w2s[(k4+0)*16+c] + v.y*w2s[(k4+1)*16+c]
            + v.z*w2s[(k4+2)*16+c] + v.w*w2s[(k4+3)*16+c];
    }
  }
  float s=0.f, t=0.f;
  #pragma unroll
  for(int c=0;c<16;c++){ s += g[c]*asw[c]; t += g[c]*adw[c]; }
  #pragma unroll
  for(int c4=0;c4<16;c4+=4)
    *(float4*)(G + n*16 + c4) = make_float4(g[c4],g[c4+1],g[c4+2],g[c4+3]);
  as2[n] = s; ad2[n] = t;
}

// GAT layer-2 gather: one wave per dst, SINGLE-PASS softmax.
// 4 edge slots x 16 channels; w identical across a slot's 16 lanes, so den
// gets the same xor(16/32) slot-reduction as acc. Self loop added after.
__global__ __launch_bounds__(TPB) void k_agg2(const int* __restrict__ offs,
                                              const int* __restrict__ col,
                                              const float* __restrict__ as2,
                                              const float* __restrict__ ad2,
                                              const float* __restrict__ G,
                                              const float* __restrict__ b2,
                                              float* __restrict__ out){
  int d = (blockIdx.x*TPB + threadIdx.x) >> 6;
  int lane = threadIdx.x & 63;
  int c = lane & 15, slot = lane >> 4;
  int beg = d ? offs[d-1] : 0;
  int end = offs[d];
  float ad2d = ad2[d];
  float den = 0.f, acc = 0.f;
  for(int j0=beg; j0<end; j0+=4){
    int j = j0 + slot;
    if(j < end){
      int s = col[j];
      float w = __expf(lrelu(as2[s] + ad2d));
      den += w;
      acc += w * G[s*16 + c];
    }
  }
  acc += __shfl_xor(acc, 16);
  acc += __shfl_xor(acc, 32);
  den += __shfl_xor(den, 16);
  den += __shfl_xor(den, 32);
  float ws = __expf(lrelu(as2[d] + ad2d));   // self loop
  den += ws;
  acc += ws * G[d*16 + c];
  if(lane < 16) out[d*16 + c] = acc / (den + 1e-16f) + b2[c];
}

// ===================== launch =====================

extern "C" void kernel_launch(void* const* d_in, const int* in_sizes, int n_in,
                              void* d_out, int out_size, void* d_ws, size_t ws_size,
                              hipStream_t stream){
  const float* x    = (const float*)d_in[0];
  const int*   ei   = (const int*)  d_in[1];
  const float* dx   = (const float*)d_in[2];
  const int*   dei  = (const int*)  d_in[3];
  const float* W1   = (const float*)d_in[4];
  const float* aw1s = (const float*)d_in[5];
  const float* aw1d = (const float*)d_in[6];
  const float* b1   = (const float*)d_in[7];
  const float* W2   = (const float*)d_in[8];
  const float* aw2s = (const float*)d_in[9];
  const float* aw2d = (const float*)d_in[10];
  const float* b2   = (const float*)d_in[11];
  const float* Wg1  = (const float*)d_in[12];
  const float* bg1  = (const float*)d_in[13];
  const float* Wg2  = (const float*)d_in[14];
  const float* bg2  = (const float*)d_in[15];

  float* out = (float*)d_out;          // [NP,16]
  float* Qo  = out + NP*NCLS;          // [NDU,16]

  float* R     = (float*)d_ws;
  float* dinvD = R + 25600000;
  int*   offsD = (int*)(dinvD + 1600000);
  int*   colD  = offsD + 1600000;
  int*   bkt   = colD + 3200000;            // 256 bucket counters

  // dual-phase overlay
  int2*   pairsD = (int2*)R;          // 3.2M int2 (dead after k_csr)
  float4* PX   = (float4*)R;          // 1.6M float4 (after k_csr)
  float*  P2   = R + 6400000;         // 12.8M words
  // primal-phase overlay
  float* H1   = R;                    // 6.4M
  float* O1   = R + 6400000;          // 6.4M
  float* G    = R + 12800000;         // 1.6M
  float* als  = R + 14400000;         // 0.8M
  float* ald  = R + 15200000;         // 0.8M
  float* as2  = R + 16000000;         // 0.1M
  float* ad2  = R + 16100000;         // 0.1M
  float* dinvP= R + 16200000;         // 0.1M (scratch; GAT doesn't use dinv)
  int*   offsP= (int*)(R + 16300000); // 0.1M
  int*   colP = offsP + 100000;       // 1.6M
  int2*  pairsP = (int2*)(R + 19200000); // 1.6M int2 = 3.2M words

  const int* dsrc = dei;
  const int* ddst = dei + EDU;
  const int* esrc = ei;
  const int* edst = ei + EP;

  const int SH_D = 13, NB_D = ((NDU - 1) >> SH_D) + 1;   // 196
  const int SH_P = 9,  NB_P = ((NP  - 1) >> SH_P) + 1;   // 196

  // ---- dual CSR build (bucketed, atomic-free CSR) ----
  hipMemsetAsync(bkt, 0, BKT_MAX*sizeof(int), stream);
  k_bhist<<<(EDU+BCHUNK-1)/BCHUNK, TPB, 0, stream>>>(ddst, bkt, EDU, SH_D);
  k_bscan<<<1, TPB, 0, stream>>>(bkt, NB_D);
  k_bscat<<<(EDU+BCHUNK-1)/BCHUNK, TPB, 0, stream>>>(dsrc, ddst, bkt, pairsD, EDU, SH_D);
  k_csr  <<<NB_D, TPB, (1<<SH_D)*sizeof(int), stream>>>(pairsD, bkt, offsD, dinvD, colD, NDU, SH_D);

  // ---- dual GCN ----
  k_pscale<<<(NDU+TPB-1)/TPB, TPB, 0, stream>>>(dx, dinvD, PX);
  k_dual1 <<<NDU*4/TPB, TPB, 0, stream>>>((const float*)PX, Wg1, bg1, dinvD, offsD, colD, P2);
  k_dual2 <<<NDU*8/TPB, TPB, 0, stream>>>(P2, Wg2, bg2, dinvD, offsD, colD, Qo);

  // ---- primal CSR build (bucketed, atomic-free CSR) ----
  hipMemsetAsync(bkt, 0, BKT_MAX*sizeof(int), stream);
  k_bhist<<<(EP+BCHUNK-1)/BCHUNK, TPB, 0, stream>>>(edst, bkt, EP, SH_P);
  k_bscan<<<1, TPB, 0, stream>>>(bkt, NB_P);
  k_bscat<<<(EP+BCHUNK-1)/BCHUNK, TPB, 0, stream>>>(esrc, edst, bkt, pairsP, EP, SH_P);
  k_csr  <<<NB_P, TPB, (1<<SH_P)*sizeof(int), stream>>>(pairsP, bkt, offsP, dinvP, colP, NP, SH_P);

  // ---- primal GAT ----
  k_gemm1<<<(NP+GBM-1)/GBM, TPB, 0, stream>>>(x, W1, H1);
  k_alpha<<<NP*NHEAD/TPB, TPB, 0, stream>>>(H1, aw1s, aw1d, als, ald);
  k_agg1 <<<NP/4, TPB, 0, stream>>>(offsP, colP, als, ald, H1, b1, O1);
  k_g    <<<(NP+TPB-1)/TPB, TPB, 0, stream>>>(O1, W2, aw2s, aw2d, G, as2, ad2);
  k_agg2 <<<NP/4, TPB, 0, stream>>>(offsP, colP, as2, ad2, G, b2, out);
}

// Round 6
// 984.573 us; speedup vs baseline: 1.9164x; 1.0905x over previous
//
#include <hip/hip_runtime.h>
#include <math.h>

// Problem constants (fixed by the reference)
#define NP    100000      // primal nodes
#define EP    1600000     // primal edges
#define NDU   1600000     // dual nodes
#define EDU   3200000     // dual edges
#define FIN   512
#define NHEAD 8
#define HIDC  8
#define NCLS  16
#define NEGS  0.2f
#define TPB   256

static __device__ __forceinline__ float lrelu(float x){ return x > 0.f ? x : NEGS*x; }

// ===================== CSR build (per-dst), bucketed, atomic-free =====================
// R1: flat fill = random-line transaction bound. R3: global atomics don't
// benefit from L2 windows (cross-XCD coherence point). R4 design: bscat makes
// bucket b's edges contiguous in pairs[]; k_csr builds deg/offs/col/dinv per
// bucket with LDS atomics + LDS scan only.

#define BKT_MAX 256   // >= bucket count (196)
#define BCHUNK  2048  // edges per block in bucket kernels (8/thread)

__global__ void k_bhist(const int* __restrict__ dst, int* __restrict__ bcnt,
                        int n, int shift){
  __shared__ int cnt[BKT_MAX];
  for(int i=threadIdx.x;i<BKT_MAX;i+=TPB) cnt[i]=0;
  __syncthreads();
  int base = blockIdx.x*BCHUNK;
  #pragma unroll
  for(int i=0;i<8;i++){
    int e = base + i*TPB + threadIdx.x;
    if(e<n) atomicAdd(&cnt[dst[e]>>shift],1);
  }
  __syncthreads();
  for(int i=threadIdx.x;i<BKT_MAX;i+=TPB) if(cnt[i]) atomicAdd(bcnt+i, cnt[i]);
}

__global__ void k_bscan(int* __restrict__ bcnt, int nb){
  __shared__ int lds[BKT_MAX];
  for(int i=threadIdx.x;i<nb;i+=TPB) lds[i]=bcnt[i];
  __syncthreads();
  if(threadIdx.x==0){ int s=0; for(int i=0;i<nb;i++){ int v=lds[i]; lds[i]=s; s+=v; } }
  __syncthreads();
  for(int i=threadIdx.x;i<nb;i+=TPB) bcnt[i]=lds[i];
}

// block-local counting scatter: edges -> bucketed (src,dst) pairs.
// After this kernel, btail[b] = END of bucket b's region.
__global__ __launch_bounds__(TPB) void k_bscat(const int* __restrict__ src,
                                               const int* __restrict__ dst,
                                               int* __restrict__ btail,
                                               int2* __restrict__ pairs,
                                               int n, int shift){
  __shared__ int cnt[BKT_MAX];
  __shared__ int bbase[BKT_MAX];
  for(int i=threadIdx.x;i<BKT_MAX;i+=TPB) cnt[i]=0;
  __syncthreads();
  int base = blockIdx.x*BCHUNK;
  int sv[8], dv[8], rv[8];
  #pragma unroll
  for(int i=0;i<8;i++){
    int e = base + i*TPB + threadIdx.x;
    if(e<n){ sv[i]=src[e]; dv[i]=dst[e]; rv[i]=atomicAdd(&cnt[dv[i]>>shift],1); }
    else rv[i]=-1;
  }
  __syncthreads();
  for(int i=threadIdx.x;i<BKT_MAX;i+=TPB){
    int c = cnt[i];
    bbase[i] = c ? atomicAdd(btail+i, c) : 0;
  }
  __syncthreads();
  #pragma unroll
  for(int i=0;i<8;i++){
    if(rv[i]>=0){
      int b = dv[i]>>shift;
      pairs[bbase[b]+rv[i]] = make_int2(sv[i], dv[i]);
    }
  }
}

// one WG per bucket: LDS hist -> LDS scan -> offs/dinv writeback -> LDS-ranked
// col scatter. Dynamic LDS: (1<<shift) ints.
__global__ __launch_bounds__(TPB) void k_csr(const int2* __restrict__ pairs,
                                             const int* __restrict__ btail,
                                             int* __restrict__ offs,
                                             float* __restrict__ dinv,
                                             int* __restrict__ col,
                                             int nnodes, int shift){
  extern __shared__ int ldeg[];
  __shared__ int ttmp[TPB];
  const int b    = blockIdx.x;
  const int tid  = threadIdx.x;
  const int ebeg = b ? btail[b-1] : 0;
  const int eend = btail[b];
  const int node0 = b << shift;
  const int W     = 1 << shift;
  const int PW    = W / TPB;

  for(int i=tid;i<W;i+=TPB) ldeg[i]=0;
  __syncthreads();
  for(int e=ebeg+tid; e<eend; e+=TPB)
    atomicAdd(&ldeg[pairs[e].y - node0], 1);
  __syncthreads();

  const int base = tid*PW;
  int s = 0;
  for(int i=0;i<PW;i++) s += ldeg[base+i];
  ttmp[tid] = s; __syncthreads();
  for(int off=1; off<TPB; off<<=1){
    int t = (tid>=off)? ttmp[tid-off] : 0;
    __syncthreads(); ttmp[tid] += t; __syncthreads();
  }
  int run = ttmp[tid] - s;

  for(int i=0;i<PW;i++){
    int d  = base + i;
    int g  = node0 + d;
    int dg = ldeg[d];
    if(g < nnodes){
      offs[g] = ebeg + run + dg;                  // inclusive
      dinv[g] = rsqrtf((float)dg + 1.0f);
    }
    ldeg[d] = ebeg + run;                         // exclusive start (global col idx)
    run += dg;
  }
  __syncthreads();

  for(int e=ebeg+tid; e<eend; e+=TPB){
    int2 p = pairs[e];
    int pos = atomicAdd(&ldeg[p.y - node0], 1);
    col[pos] = p.x;
  }
}

// ===================== dual (line-graph) GCN branch =====================
// R2: GCN is linear -> factor W out of the gather. PX = dinv*dx prescaled;
// gathers are pure channel sums; dense W-apply once per node in-register.

__global__ void k_pscale(const float* __restrict__ dx, const float* __restrict__ dinv,
                         float4* __restrict__ PX){
  int n = blockIdx.x*TPB + threadIdx.x;
  if(n >= NDU) return;
  float4 v = *(const float4*)(dx + (size_t)n*4);
  float s = dinv[n];
  PX[n] = make_float4(v.x*s, v.y*s, v.z*s, v.w*s);
}

// layer 1: 4 lanes per node (channel-parallel gather), fused W-apply.
__global__ __launch_bounds__(TPB) void k_dual1(const float* __restrict__ PX,
                                               const float* __restrict__ Wg1,
                                               const float* __restrict__ bg1,
                                               const float* __restrict__ dinv,
                                               const int* __restrict__ offs,
                                               const int* __restrict__ col,
                                               float* __restrict__ P2){
  int t = blockIdx.x*TPB + threadIdx.x;   // over NDU*4
  if(t >= NDU*4) return;
  int d = t >> 2, c = t & 3;
  int beg = d ? offs[d-1] : 0;
  int end = offs[d];
  float acc = PX[d*4 + c];                 // self loop
  for(int j=beg; j<end; j++) acc += PX[col[j]*4 + c];
  float v0 = __shfl(acc, 0, 4), v1 = __shfl(acc, 1, 4);
  float v2 = __shfl(acc, 2, 4), v3 = __shfl(acc, 3, 4);
  float di = dinv[d];
  int ch = 2*c;
  float z0 = di*(v0*Wg1[ch]   + v1*Wg1[8+ch]   + v2*Wg1[16+ch]   + v3*Wg1[24+ch])   + bg1[ch];
  float z1 = di*(v0*Wg1[ch+1] + v1*Wg1[8+ch+1] + v2*Wg1[16+ch+1] + v3*Wg1[24+ch+1]) + bg1[ch+1];
  z0 = z0 > 0.f ? z0 : 0.f;
  z1 = z1 > 0.f ? z1 : 0.f;
  *(float2*)(P2 + (size_t)d*8 + ch) = make_float2(di*z0, di*z1);
}

// layer 2: 8 lanes per node, fused W-apply -> final Qo.
__global__ __launch_bounds__(TPB) void k_dual2(const float* __restrict__ P2,
                                               const float* __restrict__ Wg2,
                                               const float* __restrict__ bg2,
                                               const float* __restrict__ dinv,
                                               const int* __restrict__ offs,
                                               const int* __restrict__ col,
                                               float* __restrict__ Qo){
  int t = blockIdx.x*TPB + threadIdx.x;   // over NDU*8
  if(t >= NDU*8) return;
  int d = t >> 3, c = t & 7;
  int beg = d ? offs[d-1] : 0;
  int end = offs[d];
  float acc = P2[d*8 + c];                 // self loop
  for(int j=beg; j<end; j++) acc += P2[col[j]*8 + c];
  float v[8];
  #pragma unroll
  for(int k=0;k<8;k++) v[k] = __shfl(acc, k, 8);
  float di = dinv[d];
  int ch = 2*c;
  float z0 = 0.f, z1 = 0.f;
  #pragma unroll
  for(int k=0;k<8;k++){
    z0 += v[k]*Wg2[k*16 + ch];
    z1 += v[k]*Wg2[k*16 + ch + 1];
  }
  *(float2*)(Qo + (size_t)d*16 + ch) = make_float2(di*z0 + bg2[ch], di*z1 + bg2[ch+1]);
}

// ===================== primal GAT branch =====================

// H = x @ W1 : [100000,512]x[512,64], fp32 register-tiled vector GEMM.
#define GBM 128
#define GBK 32
__global__ __launch_bounds__(TPB) void k_gemm1(const float* __restrict__ x,
                                               const float* __restrict__ W,
                                               float* __restrict__ H){
  __shared__ float xs[GBK][GBM+4];
  __shared__ float ws[GBK][64];
  const int tx = threadIdx.x;
  const int r0 = blockIdx.x*GBM;
  const int cg = tx & 15;
  const int rg = tx >> 4;

  float acc[8][4];
  #pragma unroll
  for(int i=0;i<8;i++)
    #pragma unroll
    for(int j=0;j<4;j++) acc[i][j] = 0.f;

  const int xrow = tx >> 3;
  const int xkc  = (tx & 7) * 4;
  const int wk = tx >> 4;
  const int wc = (tx & 15) * 4;

  for(int k0=0; k0<FIN; k0+=GBK){
    #pragma unroll
    for(int q=0;q<4;q++){
      int r  = xrow + q*32;
      int gr = r0 + r;
      float4 v = (gr < NP) ? *(const float4*)(x + (size_t)gr*FIN + k0 + xkc)
                           : make_float4(0.f,0.f,0.f,0.f);
      xs[xkc+0][r] = v.x; xs[xkc+1][r] = v.y;
      xs[xkc+2][r] = v.z; xs[xkc+3][r] = v.w;
    }
    #pragma unroll
    for(int q=0;q<2;q++){
      int k = wk + q*16;
      *(float4*)(&ws[k][wc]) = *(const float4*)(W + (size_t)(k0+k)*64 + wc);
    }
    __syncthreads();
    #pragma unroll 8
    for(int kk=0;kk<GBK;kk++){
      const float4 a0 = *(const float4*)(&xs[kk][rg*8]);
      const float4 a1 = *(const float4*)(&xs[kk][rg*8+4]);
      const float4 b  = *(const float4*)(&ws[kk][cg*4]);
      const float av[8] = {a0.x,a0.y,a0.z,a0.w,a1.x,a1.y,a1.z,a1.w};
      const float bv[4] = {b.x,b.y,b.z,b.w};
      #pragma unroll
      for(int i=0;i<8;i++)
        #pragma unroll
        for(int j=0;j<4;j++)
          acc[i][j] += av[i]*bv[j];
    }
    __syncthreads();
  }
  #pragma unroll
  for(int i=0;i<8;i++){
    int gr = r0 + rg*8 + i;
    if(gr < NP)
      *(float4*)(H + (size_t)gr*64 + cg*4) =
          make_float4(acc[i][0],acc[i][1],acc[i][2],acc[i][3]);
  }
}

__global__ void k_alpha(const float* __restrict__ H, const float* __restrict__ aw_s,
                        const float* __restrict__ aw_d,
                        float* __restrict__ als, float* __restrict__ ald){
  int i = blockIdx.x*TPB + threadIdx.x;     // over NP*8
  if(i >= NP*NHEAD) return;
  int n = i >> 3, h = i & 7;
  const float* hp = H + n*64 + h*8;
  float s = 0.f, d = 0.f;
  #pragma unroll
  for(int c=0;c<8;c++){ float v = hp[c]; s += v*aw_s[h*8+c]; d += v*aw_d[h*8+c]; }
  als[i] = s; ald[i] = d;
}

// GAT layer-1 gather: one wave per dst node, SINGLE-PASS softmax (R4),
// edge loop UNROLLED x4 with independent accumulator chains (R5).
// R5 finding: serial col->H dependent chain (~800cy/edge, 16 edges) with no
// MLP was the limiter (VALUBusy 33%, hbm 21%, nothing saturated). 4 chains
// put 12 loads in flight per iteration. den needs no cross-lane reduce (all
// 8 lanes of a head see the same w stream). Logits bounded, fp32-safe.
__global__ __launch_bounds__(TPB) void k_agg1(const int* __restrict__ offs,
                                              const int* __restrict__ col,
                                              const float* __restrict__ als,
                                              const float* __restrict__ ald,
                                              const float* __restrict__ H,
                                              const float* __restrict__ b1,
                                              float* __restrict__ O){
  int d = (blockIdx.x*TPB + threadIdx.x) >> 6;   // wave per dst
  int lane = threadIdx.x & 63;
  int hc = lane >> 3;                            // head for this channel
  int beg = d ? offs[d-1] : 0;
  int end = offs[d];
  float aldc = ald[d*8 + hc];
  float den0=0.f, den1=0.f, den2=0.f, den3=0.f;
  float acc0=0.f, acc1=0.f, acc2=0.f, acc3=0.f;
  int j = beg;
  for(; j+4<=end; j+=4){
    int s0=col[j], s1=col[j+1], s2=col[j+2], s3=col[j+3];
    float a0=als[s0*8+hc], a1=als[s1*8+hc], a2=als[s2*8+hc], a3=als[s3*8+hc];
    float h0=H[s0*64+lane], h1=H[s1*64+lane], h2=H[s2*64+lane], h3=H[s3*64+lane];
    float w0=__expf(lrelu(a0+aldc)); den0+=w0; acc0+=w0*h0;
    float w1=__expf(lrelu(a1+aldc)); den1+=w1; acc1+=w1*h1;
    float w2=__expf(lrelu(a2+aldc)); den2+=w2; acc2+=w2*h2;
    float w3=__expf(lrelu(a3+aldc)); den3+=w3; acc3+=w3*h3;
  }
  for(; j<end; j++){
    int s = col[j];
    float w = __expf(lrelu(als[s*8 + hc] + aldc));
    den0 += w;
    acc0 += w * H[s*64 + lane];
  }
  float ws = __expf(lrelu(als[d*8 + hc] + aldc));  // self loop
  float den = ((den0+den1)+(den2+den3)) + ws;
  float acc = ((acc0+acc1)+(acc2+acc3)) + ws * H[d*64 + lane];
  float v = acc / (den + 1e-16f) + b1[lane];
  O[d*64 + lane] = v > 0.f ? v : expm1f(v);        // ELU fused
}

// G = O @ W2 ([64][16]) + layer-2 attention logits (heads=1)
__global__ void k_g(const float* __restrict__ O, const float* __restrict__ W2,
                    const float* __restrict__ asw, const float* __restrict__ adw,
                    float* __restrict__ G, float* __restrict__ as2, float* __restrict__ ad2){
  __shared__ float w2s[64*NCLS];
  for(int i=threadIdx.x; i<64*NCLS; i+=TPB) w2s[i] = W2[i];
  __syncthreads();
  int n = blockIdx.x*TPB + threadIdx.x;
  if(n >= NP) return;
  float g[16];
  #pragma unroll
  for(int c=0;c<16;c++) g[c] = 0.f;
  const float* op = O + n*64;
  #pragma unroll
  for(int k4=0;k4<64;k4+=4){
    float4 v = *(const float4*)(op + k4);
    #pragma unroll
    for(int c=0;c<16;c++){
      g[c] += v.x*w2s[(k4+0)*16+c] + v.y*w2s[(k4+1)*16+c]
            + v.z*w2s[(k4+2)*16+c] + v.w*w2s[(k4+3)*16+c];
    }
  }
  float s=0.f, t=0.f;
  #pragma unroll
  for(int c=0;c<16;c++){ s += g[c]*asw[c]; t += g[c]*adw[c]; }
  #pragma unroll
  for(int c4=0;c4<16;c4+=4)
    *(float4*)(G + n*16 + c4) = make_float4(g[c4],g[c4+1],g[c4+2],g[c4+3]);
  as2[n] = s; ad2[n] = t;
}

// GAT layer-2 gather: one wave per dst, SINGLE-PASS softmax, 2 independent
// chains per lane (slots stride 8: slot and slot+4).
__global__ __launch_bounds__(TPB) void k_agg2(const int* __restrict__ offs,
                                              const int* __restrict__ col,
                                              const float* __restrict__ as2,
                                              const float* __restrict__ ad2,
                                              const float* __restrict__ G,
                                              const float* __restrict__ b2,
                                              float* __restrict__ out){
  int d = (blockIdx.x*TPB + threadIdx.x) >> 6;
  int lane = threadIdx.x & 63;
  int c = lane & 15, slot = lane >> 4;
  int beg = d ? offs[d-1] : 0;
  int end = offs[d];
  float ad2d = ad2[d];
  float den0=0.f, den1=0.f, acc0=0.f, acc1=0.f;
  for(int j0=beg; j0<end; j0+=8){
    int ja = j0 + slot;
    int jb = ja + 4;
    if(ja < end){
      int s = col[ja];
      float w = __expf(lrelu(as2[s] + ad2d));
      den0 += w; acc0 += w * G[s*16 + c];
    }
    if(jb < end){
      int s = col[jb];
      float w = __expf(lrelu(as2[s] + ad2d));
      den1 += w; acc1 += w * G[s*16 + c];
    }
  }
  float acc = acc0 + acc1, den = den0 + den1;
  acc += __shfl_xor(acc, 16);
  acc += __shfl_xor(acc, 32);
  den += __shfl_xor(den, 16);
  den += __shfl_xor(den, 32);
  float ws = __expf(lrelu(as2[d] + ad2d));   // self loop
  den += ws;
  acc += ws * G[d*16 + c];
  if(lane < 16) out[d*16 + c] = acc / (den + 1e-16f) + b2[c];
}

// ===================== launch =====================

extern "C" void kernel_launch(void* const* d_in, const int* in_sizes, int n_in,
                              void* d_out, int out_size, void* d_ws, size_t ws_size,
                              hipStream_t stream){
  const float* x    = (const float*)d_in[0];
  const int*   ei   = (const int*)  d_in[1];
  const float* dx   = (const float*)d_in[2];
  const int*   dei  = (const int*)  d_in[3];
  const float* W1   = (const float*)d_in[4];
  const float* aw1s = (const float*)d_in[5];
  const float* aw1d = (const float*)d_in[6];
  const float* b1   = (const float*)d_in[7];
  const float* W2   = (const float*)d_in[8];
  const float* aw2s = (const float*)d_in[9];
  const float* aw2d = (const float*)d_in[10];
  const float* b2   = (const float*)d_in[11];
  const float* Wg1  = (const float*)d_in[12];
  const float* bg1  = (const float*)d_in[13];
  const float* Wg2  = (const float*)d_in[14];
  const float* bg2  = (const float*)d_in[15];

  float* out = (float*)d_out;          // [NP,16]
  float* Qo  = out + NP*NCLS;          // [NDU,16]

  float* R     = (float*)d_ws;
  float* dinvD = R + 25600000;
  int*   offsD = (int*)(dinvD + 1600000);
  int*   colD  = offsD + 1600000;
  int*   bkt   = colD + 3200000;            // 256 bucket counters

  // dual-phase overlay
  int2*   pairsD = (int2*)R;          // 3.2M int2 (dead after k_csr)
  float4* PX   = (float4*)R;          // 1.6M float4 (after k_csr)
  float*  P2   = R + 6400000;         // 12.8M words
  // primal-phase overlay
  float* H1   = R;                    // 6.4M
  float* O1   = R + 6400000;          // 6.4M
  float* G    = R + 12800000;         // 1.6M
  float* als  = R + 14400000;         // 0.8M
  float* ald  = R + 15200000;         // 0.8M
  float* as2  = R + 16000000;         // 0.1M
  float* ad2  = R + 16100000;         // 0.1M
  float* dinvP= R + 16200000;         // 0.1M (scratch; GAT doesn't use dinv)
  int*   offsP= (int*)(R + 16300000); // 0.1M
  int*   colP = offsP + 100000;       // 1.6M
  int2*  pairsP = (int2*)(R + 19200000); // 1.6M int2 = 3.2M words

  const int* dsrc = dei;
  const int* ddst = dei + EDU;
  const int* esrc = ei;
  const int* edst = ei + EP;

  const int SH_D = 13, NB_D = ((NDU - 1) >> SH_D) + 1;   // 196
  const int SH_P = 9,  NB_P = ((NP  - 1) >> SH_P) + 1;   // 196

  // ---- dual CSR build (bucketed, atomic-free CSR) ----
  hipMemsetAsync(bkt, 0, BKT_MAX*sizeof(int), stream);
  k_bhist<<<(EDU+BCHUNK-1)/BCHUNK, TPB, 0, stream>>>(ddst, bkt, EDU, SH_D);
  k_bscan<<<1, TPB, 0, stream>>>(bkt, NB_D);
  k_bscat<<<(EDU+BCHUNK-1)/BCHUNK, TPB, 0, stream>>>(dsrc, ddst, bkt, pairsD, EDU, SH_D);
  k_csr  <<<NB_D, TPB, (1<<SH_D)*sizeof(int), stream>>>(pairsD, bkt, offsD, dinvD, colD, NDU, SH_D);

  // ---- dual GCN ----
  k_pscale<<<(NDU+TPB-1)/TPB, TPB, 0, stream>>>(dx, dinvD, PX);
  k_dual1 <<<NDU*4/TPB, TPB, 0, stream>>>((const float*)PX, Wg1, bg1, dinvD, offsD, colD, P2);
  k_dual2 <<<NDU*8/TPB, TPB, 0, stream>>>(P2, Wg2, bg2, dinvD, offsD, colD, Qo);

  // ---- primal CSR build (bucketed, atomic-free CSR) ----
  hipMemsetAsync(bkt, 0, BKT_MAX*sizeof(int), stream);
  k_bhist<<<(EP+BCHUNK-1)/BCHUNK, TPB, 0, stream>>>(edst, bkt, EP, SH_P);
  k_bscan<<<1, TPB, 0, stream>>>(bkt, NB_P);
  k_bscat<<<(EP+BCHUNK-1)/BCHUNK, TPB, 0, stream>>>(esrc, edst, bkt, pairsP, EP, SH_P);
  k_csr  <<<NB_P, TPB, (1<<SH_P)*sizeof(int), stream>>>(pairsP, bkt, offsP, dinvP, colP, NP, SH_P);

  // ---- primal GAT ----
  k_gemm1<<<(NP+GBM-1)/GBM, TPB, 0, stream>>>(x, W1, H1);
  k_alpha<<<NP*NHEAD/TPB, TPB, 0, stream>>>(H1, aw1s, aw1d, als, ald);
  k_agg1 <<<NP/4, TPB, 0, stream>>>(offsP, colP, als, ald, H1, b1, O1);
  k_g    <<<(NP+TPB-1)/TPB, TPB, 0, stream>>>(O1, W2, aw2s, aw2d, G, as2, ad2);
  k_agg2 <<<NP/4, TPB, 0, stream>>>(offsP, colP, as2, ad2, G, b2, out);
}